// Round 1
// baseline (595.837 us; speedup 1.0000x reference)
//
#include <hip/hip_runtime.h>

#define B_  4
#define S_  2048
#define D_  1024
#define H_  16
#define DK_ 64

typedef unsigned short ushort;
typedef __attribute__((ext_vector_type(8))) short short8;
typedef __attribute__((ext_vector_type(8))) unsigned short ushort8;
typedef __attribute__((ext_vector_type(4))) float f32x4;

// scores use exp2: fold 0.125 * log2(e) into Q at projection time
#define QSCALE 0.18033688011112042f

__device__ __forceinline__ ushort f2bf(float f) {  // RNE
    unsigned int u = __float_as_uint(f);
    u += 0x7fffu + ((u >> 16) & 1u);
    return (ushort)(u >> 16);
}

__device__ __forceinline__ unsigned cvt_pk_bf16(float lo, float hi) {
    unsigned r;
    asm("v_cvt_pk_bf16_f32 %0, %1, %2" : "=v"(r) : "v"(lo), "v"(hi));
    return r;
}
// swaps a[32:63] <-> b[0:31]
__device__ __forceinline__ void pl32_swap(unsigned& a, unsigned& b) {
    asm("v_permlane32_swap_b32 %0, %1" : "+v"(a), "+v"(b));
}
__device__ __forceinline__ short8 mk8(unsigned a, unsigned b, unsigned c,
                                      unsigned d) {
    union { unsigned u[4]; short8 s; } x;
    x.u[0] = a; x.u[1] = b; x.u[2] = c; x.u[3] = d;
    return x.s;
}

__device__ __forceinline__ void gl_lds16(const ushort* g, ushort* ldsbase) {
    __builtin_amdgcn_global_load_lds(
        (const __attribute__((address_space(1))) void*)g,
        (__attribute__((address_space(3))) void*)ldsbase, 16, 0, 0);
}

// ---------------------------------------------------------------------------
// Cast q,k,v + Wq,Wk,Wv,Wo to bf16 in one launch.
// ---------------------------------------------------------------------------
__global__ __launch_bounds__(256) void cast_all(
    const float* __restrict__ q, const float* __restrict__ k,
    const float* __restrict__ v, const float* __restrict__ Wq,
    const float* __restrict__ Wk, const float* __restrict__ Wv,
    const float* __restrict__ Wo, ushort* __restrict__ qkv_dst,
    ushort* __restrict__ w_dst) {
    const int bid = blockIdx.x;
    const float* src;
    ushort* dst;
    int lb;
    if (bid < 12288) {
        const int s = bid >> 12;
        lb = bid & 4095;
        src = (s == 0) ? q : (s == 1) ? k : v;
        dst = qkv_dst + (size_t)s * (B_ * S_ * D_);
    } else {
        const int wi = (bid - 12288) >> 9;
        lb = (bid - 12288) & 511;
        src = (wi == 0) ? Wq : (wi == 1) ? Wk : (wi == 2) ? Wv : Wo;
        dst = w_dst + (size_t)wi * (D_ * D_);
    }
    const int i = lb * 2048 + threadIdx.x * 8;
    const float4 a = *(const float4*)(src + i);
    const float4 b = *(const float4*)(src + i + 4);
    ushort8 r;
    r[0] = f2bf(a.x); r[1] = f2bf(a.y); r[2] = f2bf(a.z); r[3] = f2bf(a.w);
    r[4] = f2bf(b.x); r[5] = f2bf(b.y); r[6] = f2bf(b.z); r[7] = f2bf(b.w);
    *(ushort8*)(dst + i) = r;
}

// ---------------------------------------------------------------------------
// int32 mask -> 1 bit per element (bit i of word = k position). 2 MB total.
// ---------------------------------------------------------------------------
__global__ __launch_bounds__(256) void mask_bits_kernel(
    const int* __restrict__ m, unsigned long long* __restrict__ bits) {
    const size_t idx = (size_t)blockIdx.x * 256 + threadIdx.x;
    const unsigned long long bal = __ballot(m[idx] != 0);
    if ((threadIdx.x & 63) == 0) bits[idx >> 6] = bal;
}

// ---------------------------------------------------------------------------
// Fused Q/K/V projection (blockIdx.z selects). out = (A @ W^T + b)*scale,
// bf16 scatter to [B,H,S,DK] (uniform, coalesced 32B runs).
// ---------------------------------------------------------------------------
__global__ __launch_bounds__(256) void gemm_proj(
    const ushort* __restrict__ qb, const ushort* __restrict__ kb,
    const ushort* __restrict__ vb, const ushort* __restrict__ Wb,
    const float* __restrict__ bq, const float* __restrict__ bk,
    const float* __restrict__ bv, ushort* __restrict__ Qd,
    ushort* __restrict__ Kd, ushort* __restrict__ Vd) {
    const int z = blockIdx.z;
    const ushort* A  = (z == 0) ? qb : (z == 1) ? kb : vb;
    const ushort* Wm = Wb + (size_t)z * (D_ * D_);
    const float* bias = (z == 0) ? bq : (z == 1) ? bk : bv;
    ushort* outp = (z == 0) ? Qd : (z == 1) ? Kd : Vd;
    const float scale = (z == 0) ? QSCALE : 1.0f;

    __shared__ ushort As[128 * 32];
    __shared__ ushort Bs[128 * 32];
    const int t = threadIdx.x, w = t >> 6, lane = t & 63;
    const int ln15 = lane & 15, quad = lane >> 4;
    const int wr = w >> 1, wc = w & 1;
    const int n0 = blockIdx.x * 128, m0 = blockIdx.y * 128;
    const int srow = lane >> 2;
    const int sg = (lane & 3) * 8;

    f32x4 acc[4][4] = {};
    for (int k0 = 0; k0 < D_; k0 += 32) {
#pragma unroll
        for (int c = 0; c < 2; ++c) {
            const int cc = w * 2 + c;
            const int row = cc * 16 + srow;
            gl_lds16(A + (size_t)(m0 + row) * D_ + k0 + sg, As + cc * 512);
            gl_lds16(Wm + (size_t)(n0 + row) * D_ + k0 + sg, Bs + cc * 512);
        }
        __syncthreads();
        short8 af[4], bf[4];
#pragma unroll
        for (int i = 0; i < 4; ++i) {
            af[i] = *(const short8*)(As + (wr * 64 + i * 16 + ln15) * 32 + quad * 8);
            bf[i] = *(const short8*)(Bs + (wc * 64 + i * 16 + ln15) * 32 + quad * 8);
        }
#pragma unroll
        for (int mt = 0; mt < 4; ++mt)
#pragma unroll
            for (int nt = 0; nt < 4; ++nt)
                acc[mt][nt] = __builtin_amdgcn_mfma_f32_16x16x32_bf16(
                    af[mt], bf[nt], acc[mt][nt], 0, 0, 0);
        __syncthreads();
    }
#pragma unroll
    for (int mt = 0; mt < 4; ++mt) {
#pragma unroll
        for (int r = 0; r < 4; ++r) {
            const int row = m0 + wr * 64 + mt * 16 + quad * 4 + r;
            const int bb = row >> 11, s = row & (S_ - 1);
#pragma unroll
            for (int nt = 0; nt < 4; ++nt) {
                const int col = n0 + wc * 64 + nt * 16 + ln15;
                const float vv = (acc[mt][nt][r] + bias[col]) * scale;
                const int h = col >> 6, dk = col & 63;
                outp[((((size_t)bb * H_ + h) * S_ + s) << 6) + dk] = f2bf(vv);
            }
        }
    }
}

// ---------------------------------------------------------------------------
// V [bh][s][dk] -> V^T [bh][dk][s]. Two layers of key permutation within each
// 64-key window so attn can form PV A-fragments in-register:
//   (1) kappa(sg,m): key order matching the permlane32-swap output of attn's
//       packed P registers; (2) XOR-swizzle of 8-key groups (pg = sg^(dk&7))
//       matching attn's async staging + swizzled ds_read.
// ---------------------------------------------------------------------------
__global__ __launch_bounds__(256) void vtrans(const ushort* __restrict__ Vs_,
                                              ushort* __restrict__ Vt_) {
    __shared__ ushort L[64 * 76];
    const int t = threadIdx.x;
    const int bh = blockIdx.y;
    const int s0 = blockIdx.x * 64;
    const ushort* src = Vs_ + (size_t)bh * S_ * DK_;
    ushort* dst = Vt_ + (size_t)bh * DK_ * S_;
    const int r = t >> 2, g = t & 3;
#pragma unroll
    for (int gg = 0; gg < 2; ++gg) {
        const int grp = g + gg * 4;
        const ushort8 v = *(const ushort8*)(src + (size_t)(s0 + r) * DK_ + grp * 8);
        *(ushort8*)(&L[r * 76 + grp * 8]) = v;
    }
    __syncthreads();
    const int dim = t >> 2;
    const int OFF[8] = {0, 1, 8, 9, 2, 3, 10, 11};
#pragma unroll
    for (int gg = 0; gg < 2; ++gg) {
        const int sg = g + gg * 4;          // logical storage group
        const int ks = sg >> 2, g2 = sg & 3;
        const int kb = ks * 32 + g2 * 4 + (g2 >> 1) * 8;
        ushort8 o;
#pragma unroll
        for (int j = 0; j < 8; ++j) o[j] = L[(kb + OFF[j]) * 76 + dim];
        const int pg = sg ^ (dim & 7);      // physical (swizzled) slot
        *(ushort8*)(dst + (size_t)dim * S_ + s0 + pg * 8) = o;
    }
}

// ---------------------------------------------------------------------------
// Output projection: fp32 out = A @ W^T + b, flat [M,D]
// ---------------------------------------------------------------------------
__global__ __launch_bounds__(256) void gemm_out(const ushort* __restrict__ A,
                                                const ushort* __restrict__ Wm,
                                                const float* __restrict__ bias,
                                                float* __restrict__ out) {
    __shared__ ushort As[128 * 32];
    __shared__ ushort Bs[128 * 32];
    const int t = threadIdx.x, w = t >> 6, lane = t & 63;
    const int ln15 = lane & 15, quad = lane >> 4;
    const int wr = w >> 1, wc = w & 1;
    const int n0 = blockIdx.x * 128, m0 = blockIdx.y * 128;
    const int srow = lane >> 2;
    const int sg = (lane & 3) * 8;

    f32x4 acc[4][4] = {};
    for (int k0 = 0; k0 < D_; k0 += 32) {
#pragma unroll
        for (int c = 0; c < 2; ++c) {
            const int cc = w * 2 + c;
            const int row = cc * 16 + srow;
            gl_lds16(A + (size_t)(m0 + row) * D_ + k0 + sg, As + cc * 512);
            gl_lds16(Wm + (size_t)(n0 + row) * D_ + k0 + sg, Bs + cc * 512);
        }
        __syncthreads();
        short8 af[4], bf[4];
#pragma unroll
        for (int i = 0; i < 4; ++i) {
            af[i] = *(const short8*)(As + (wr * 64 + i * 16 + ln15) * 32 + quad * 8);
            bf[i] = *(const short8*)(Bs + (wc * 64 + i * 16 + ln15) * 32 + quad * 8);
        }
#pragma unroll
        for (int mt = 0; mt < 4; ++mt)
#pragma unroll
            for (int nt = 0; nt < 4; ++nt)
                acc[mt][nt] = __builtin_amdgcn_mfma_f32_16x16x32_bf16(
                    af[mt], bf[nt], acc[mt][nt], 0, 0, 0);
        __syncthreads();
    }
#pragma unroll
    for (int mt = 0; mt < 4; ++mt) {
#pragma unroll
        for (int r = 0; r < 4; ++r) {
            const int row = m0 + wr * 64 + mt * 16 + quad * 4 + r;
#pragma unroll
            for (int nt = 0; nt < 4; ++nt) {
                const int col = n0 + wc * 64 + nt * 16 + ln15;
                out[(size_t)row * D_ + col] = acc[mt][nt][r] + bias[col];
            }
        }
    }
}

// ---------------------------------------------------------------------------
// Flash attention, no-LDS P path.
//   QK^T computed SWAPPED (mfma(K,Q)) so each lane holds S[key][qrow=ln15];
//   mask+exp2 in place, v_cvt_pk_bf16_f32 pairs, v_permlane32_swap x8 forms
//   the PV A-fragment entirely in registers (key permutation folded into
//   vtrans). LDS = Ks dbuf + Vt dbuf, padded to 40960 B -> exactly 4 blk/CU;
//   grid 1024 = 256 CU x 4 -> all blocks co-resident, no tail phase.
// ---------------------------------------------------------------------------
__global__ __launch_bounds__(256, 4) void attn_mfma(
    const ushort* __restrict__ Qd, const ushort* __restrict__ Kd,
    const ushort* __restrict__ Vtg, const unsigned long long* __restrict__ bits,
    ushort* __restrict__ ctx) {
    __shared__ ushort Ks[2][64 * 64 + 1024];  // [key][dk], swizzled groups (+pad)
    __shared__ ushort Vt[2][64 * 64 + 1024];  // [dk][key], swizzled groups (+pad)

    const int t = threadIdx.x, w = t >> 6, lane = t & 63;
    const int ln15 = lane & 15, quad = lane >> 4, q4 = quad * 4;
    const int lp = lane & 7, lr8 = lane >> 3;
    const int bh = blockIdx.y, b = bh >> 4, h = bh & 15;
    const int q0 = blockIdx.x * 128;

    const ushort* Qb = Qd + (size_t)bh * (S_ * DK_);
    const ushort* Kb = Kd + (size_t)bh * (S_ * DK_);
    const ushort* Vb = Vtg + (size_t)bh * (DK_ * S_);  // [dk][s] swizzled
    const unsigned long long* mbits = bits + (size_t)b * S_ * (S_ / 64);

    // mask word per qrow: qrow = q0 + w*32 + mt*16 + ln15 (2 words per lane)
    int mof[2];
#pragma unroll
    for (int mt = 0; mt < 2; ++mt)
        mof[mt] = (q0 + w * 32 + mt * 16 + ln15) * (S_ / 64);

    // Q fragments: loaded once, live in registers all kernel (B-operand now)
    short8 aq[2][2];  // [ks][mt]
#pragma unroll
    for (int ks = 0; ks < 2; ++ks)
#pragma unroll
        for (int mt = 0; mt < 2; ++mt)
            aq[ks][mt] = *(const short8*)(
                Qb + (size_t)(q0 + w * 32 + mt * 16 + ln15) * DK_ + ks * 32 + quad * 8);

    // stage K/V tile kt into buffer p (async; drained by the NEXT barrier)
    auto stageKV = [&](int kt, int p) {
        const int k0 = kt * 64;
#pragma unroll
        for (int c = 0; c < 2; ++c) {
            const int cc = w * 2 + c;
            const int row = cc * 8 + lr8;  // K: key row; V: dk row
            gl_lds16(Kb + (size_t)(k0 + row) * DK_ + (lp ^ lr8) * 8, &Ks[p][cc * 512]);
            gl_lds16(Vb + (size_t)row * S_ + k0 + lp * 8, &Vt[p][cc * 512]);
        }
    };

    stageKV(0, 0);
    unsigned long long mw[2];
    mw[0] = mbits[mof[0]];
    mw[1] = mbits[mof[1]];

    f32x4 O[2][4] = {};
    f32x4 lsum[2] = {};
    short8 vone;
#pragma unroll
    for (int j = 0; j < 8; ++j) vone[j] = (short)0x3F80;  // bf16(1.0)

    int p = 0;
    for (int kt = 0; kt < S_ / 64; ++kt) {
        __syncthreads();  // drains stageKV(kt); buffer p^1 now free
        if (kt < S_ / 64 - 1) stageKV(kt + 1, p ^ 1);

        // ---- S'^T = K (Q*QSCALE)^T : lane holds S[key=16nt+q4+r][qrow=16mt+ln15]
        f32x4 sc[2][4] = {};
#pragma unroll
        for (int ks = 0; ks < 2; ++ks) {
            short8 bk[4];
#pragma unroll
            for (int nt = 0; nt < 4; ++nt) {
                const int row = nt * 16 + ln15;
                bk[nt] = *(const short8*)(&Ks[p][row * 64 + ((ks * 4 + quad) ^ (row & 7)) * 8]);
            }
#pragma unroll
            for (int mt = 0; mt < 2; ++mt)
#pragma unroll
                for (int nt = 0; nt < 4; ++nt)
                    sc[mt][nt] = __builtin_amdgcn_mfma_f32_16x16x32_bf16(
                        bk[nt], aq[ks][mt], sc[mt][nt], 0, 0, 0);
        }

        // ---- P = maskbit ? exp2(S') : 0 -> pack bf16 pairs -> permlane32
        // exchange into PV A-fragments. No LDS round trip.
        short8 ap[2][2];  // [mt][ks]
#pragma unroll
        for (int mt = 0; mt < 2; ++mt) {
            unsigned pk[4][2];
#pragma unroll
            for (int nt = 0; nt < 4; ++nt) {
                float pv[4];
#pragma unroll
                for (int r = 0; r < 4; ++r) {
                    const float e = __builtin_amdgcn_exp2f(sc[mt][nt][r]);
                    pv[r] = ((mw[mt] >> (nt * 16 + q4 + r)) & 1ull) ? e : 0.0f;
                }
                pk[nt][0] = cvt_pk_bf16(pv[0], pv[1]);
                pk[nt][1] = cvt_pk_bf16(pv[2], pv[3]);
            }
            // after swap: pk[2ks][h] = A'-word, pk[2ks+1][h] = B'-word
            pl32_swap(pk[0][0], pk[1][0]);
            pl32_swap(pk[0][1], pk[1][1]);
            pl32_swap(pk[2][0], pk[3][0]);
            pl32_swap(pk[2][1], pk[3][1]);
            ap[mt][0] = mk8(pk[0][0], pk[1][0], pk[0][1], pk[1][1]);
            ap[mt][1] = mk8(pk[2][0], pk[3][0], pk[2][1], pk[3][1]);
        }

        // prefetch mask for kt+1
        if (kt < S_ / 64 - 1) {
            mw[0] = mbits[mof[0] + kt + 1];
            mw[1] = mbits[mof[1] + kt + 1];
        }

        // ---- O += P V^T ; lsum += P @ ones
#pragma unroll
        for (int ks = 0; ks < 2; ++ks) {
            short8 bv4[4];
#pragma unroll
            for (int nt = 0; nt < 4; ++nt) {
                const int dim = nt * 16 + ln15;
                bv4[nt] = *(const short8*)(&Vt[p][dim * 64 + ((ks * 4 + quad) ^ (dim & 7)) * 8]);
            }
#pragma unroll
            for (int mt = 0; mt < 2; ++mt) {
#pragma unroll
                for (int nt = 0; nt < 4; ++nt)
                    O[mt][nt] = __builtin_amdgcn_mfma_f32_16x16x32_bf16(
                        ap[mt][ks], bv4[nt], O[mt][nt], 0, 0, 0);
                lsum[mt] = __builtin_amdgcn_mfma_f32_16x16x32_bf16(
                    ap[mt][ks], vone, lsum[mt], 0, 0, 0);
            }
        }
        p ^= 1;
    }

    // finalize: ctx[b][s][h*64+dim] = O / lsum (bf16, feeds out-proj)
#pragma unroll
    for (int mt = 0; mt < 2; ++mt) {
#pragma unroll
        for (int r = 0; r < 4; ++r) {
            const int qg = q0 + w * 32 + mt * 16 + quad * 4 + r;
            const float inv = __builtin_amdgcn_rcpf(lsum[mt][r]);
#pragma unroll
            for (int nt = 0; nt < 4; ++nt) {
                const int dim = nt * 16 + ln15;
                ctx[((size_t)b * S_ + qg) * D_ + h * DK_ + dim] = f2bf(O[mt][nt][r] * inv);
            }
        }
    }
}

// ---------------------------------------------------------------------------
extern "C" void kernel_launch(void* const* d_in, const int* in_sizes, int n_in,
                              void* d_out, int out_size, void* d_ws, size_t ws_size,
                              hipStream_t stream) {
    (void)in_sizes; (void)n_in; (void)out_size; (void)ws_size;
    const float* query = (const float*)d_in[0];
    const float* key_  = (const float*)d_in[1];
    const float* value = (const float*)d_in[2];
    const int*   mask  = (const int*)d_in[3];
    const float* Wq = (const float*)d_in[4];
    const float* bq = (const float*)d_in[5];
    const float* Wk = (const float*)d_in[6];
    const float* bk = (const float*)d_in[7];
    const float* Wv = (const float*)d_in[8];
    const float* bv = (const float*)d_in[9];
    const float* Wo = (const float*)d_in[10];
    const float* bo = (const float*)d_in[11];
    float* out = (float*)d_out;

    const size_t nX = (size_t)B_ * S_ * D_;  // 8,388,608
    const size_t nW = (size_t)D_ * D_;       // 1,048,576
    ushort* qkv = (ushort*)d_ws;       // 3*nX bf16 (q,k,v casts)
    ushort* Wb  = qkv + 3 * nX;        // 4*nW bf16
    ushort* Qd  = Wb + 4 * nW;
    ushort* Kd  = Qd + nX;
    ushort* Vd  = Kd + nX;             // standard [B,H,S,DK]
    unsigned long long* bits = (unsigned long long*)(Vd + nX);  // 2 MB
    ushort* ctx = qkv;                 // q-cast region, dead after gemm_proj
    ushort* VtT = qkv + 2 * nX;        // v-cast region, dead after gemm_proj

    cast_all<<<14336, 256, 0, stream>>>(query, key_, value, Wq, Wk, Wv, Wo, qkv, Wb);
    mask_bits_kernel<<<B_ * S_ * S_ / 256, 256, 0, stream>>>(mask, bits);

    dim3 gp(D_ / 128, (B_ * S_) / 128, 3);  // (8, 64, 3)
    gemm_proj<<<gp, 256, 0, stream>>>(qkv, qkv + nX, qkv + 2 * nX, Wb,
                                      bq, bk, bv, Qd, Kd, Vd);

    dim3 gv(S_ / 64, B_ * H_);  // (32, 64)
    vtrans<<<gv, 256, 0, stream>>>(Vd, VtT);

    dim3 ga(S_ / 128, B_ * H_);  // (16, 64)
    attn_mfma<<<ga, 256, 0, stream>>>(Qd, Kd, VtT, bits, ctx);

    dim3 go(D_ / 128, (B_ * S_) / 128);  // (8, 64)
    gemm_out<<<go, 256, 0, stream>>>(ctx, Wb + 3 * nW, bo, out);
}

// Round 2
// 456.507 us; speedup vs baseline: 1.3052x; 1.3052x over previous
//
#include <hip/hip_runtime.h>

#define B_  4
#define S_  2048
#define D_  1024
#define H_  16
#define DK_ 64

typedef unsigned short ushort;
typedef __attribute__((ext_vector_type(8))) short short8;
typedef __attribute__((ext_vector_type(8))) unsigned short ushort8;
typedef __attribute__((ext_vector_type(4))) float f32x4;

// scores use exp2: fold 0.125 * log2(e) into Q at projection time
#define QSCALE 0.18033688011112042f

__device__ __forceinline__ ushort f2bf(float f) {  // RNE
    unsigned int u = __float_as_uint(f);
    u += 0x7fffu + ((u >> 16) & 1u);
    return (ushort)(u >> 16);
}

__device__ __forceinline__ unsigned cvt_pk_bf16(float lo, float hi) {
    unsigned r;
    asm("v_cvt_pk_bf16_f32 %0, %1, %2" : "=v"(r) : "v"(lo), "v"(hi));
    return r;
}
// swaps a[32:63] <-> b[0:31]
__device__ __forceinline__ void pl32_swap(unsigned& a, unsigned& b) {
    asm("v_permlane32_swap_b32 %0, %1" : "+v"(a), "+v"(b));
}
__device__ __forceinline__ short8 mk8(unsigned a, unsigned b, unsigned c,
                                      unsigned d) {
    union { unsigned u[4]; short8 s; } x;
    x.u[0] = a; x.u[1] = b; x.u[2] = c; x.u[3] = d;
    return x.s;
}

__device__ __forceinline__ void gl_lds16(const ushort* g, ushort* ldsbase) {
    __builtin_amdgcn_global_load_lds(
        (const __attribute__((address_space(1))) void*)g,
        (__attribute__((address_space(3))) void*)ldsbase, 16, 0, 0);
}

// ---------------------------------------------------------------------------
// Cast q,k,v + Wq,Wk,Wv,Wo to bf16 in one launch.
// ---------------------------------------------------------------------------
__global__ __launch_bounds__(256) void cast_all(
    const float* __restrict__ q, const float* __restrict__ k,
    const float* __restrict__ v, const float* __restrict__ Wq,
    const float* __restrict__ Wk, const float* __restrict__ Wv,
    const float* __restrict__ Wo, ushort* __restrict__ qkv_dst,
    ushort* __restrict__ w_dst) {
    const int bid = blockIdx.x;
    const float* src;
    ushort* dst;
    int lb;
    if (bid < 12288) {
        const int s = bid >> 12;
        lb = bid & 4095;
        src = (s == 0) ? q : (s == 1) ? k : v;
        dst = qkv_dst + (size_t)s * (B_ * S_ * D_);
    } else {
        const int wi = (bid - 12288) >> 9;
        lb = (bid - 12288) & 511;
        src = (wi == 0) ? Wq : (wi == 1) ? Wk : (wi == 2) ? Wv : Wo;
        dst = w_dst + (size_t)wi * (D_ * D_);
    }
    const int i = lb * 2048 + threadIdx.x * 8;
    const float4 a = *(const float4*)(src + i);
    const float4 b = *(const float4*)(src + i + 4);
    ushort8 r;
    r[0] = f2bf(a.x); r[1] = f2bf(a.y); r[2] = f2bf(a.z); r[3] = f2bf(a.w);
    r[4] = f2bf(b.x); r[5] = f2bf(b.y); r[6] = f2bf(b.z); r[7] = f2bf(b.w);
    *(ushort8*)(dst + i) = r;
}

// ---------------------------------------------------------------------------
// int32 mask -> 1 bit per element (bit i of word = k position). 2 MB total.
// ---------------------------------------------------------------------------
__global__ __launch_bounds__(256) void mask_bits_kernel(
    const int* __restrict__ m, unsigned long long* __restrict__ bits) {
    const size_t idx = (size_t)blockIdx.x * 256 + threadIdx.x;
    const unsigned long long bal = __ballot(m[idx] != 0);
    if ((threadIdx.x & 63) == 0) bits[idx >> 6] = bal;
}

// ---------------------------------------------------------------------------
// Fused Q/K/V projection (blockIdx.z selects). out = (A @ W^T + b)*scale,
// bf16 scatter to [B,H,S,DK] (uniform, coalesced 32B runs).
// ---------------------------------------------------------------------------
__global__ __launch_bounds__(256) void gemm_proj(
    const ushort* __restrict__ qb, const ushort* __restrict__ kb,
    const ushort* __restrict__ vb, const ushort* __restrict__ Wb,
    const float* __restrict__ bq, const float* __restrict__ bk,
    const float* __restrict__ bv, ushort* __restrict__ Qd,
    ushort* __restrict__ Kd, ushort* __restrict__ Vd) {
    const int z = blockIdx.z;
    const ushort* A  = (z == 0) ? qb : (z == 1) ? kb : vb;
    const ushort* Wm = Wb + (size_t)z * (D_ * D_);
    const float* bias = (z == 0) ? bq : (z == 1) ? bk : bv;
    ushort* outp = (z == 0) ? Qd : (z == 1) ? Kd : Vd;
    const float scale = (z == 0) ? QSCALE : 1.0f;

    __shared__ ushort As[128 * 32];
    __shared__ ushort Bs[128 * 32];
    const int t = threadIdx.x, w = t >> 6, lane = t & 63;
    const int ln15 = lane & 15, quad = lane >> 4;
    const int wr = w >> 1, wc = w & 1;
    const int n0 = blockIdx.x * 128, m0 = blockIdx.y * 128;
    const int srow = lane >> 2;
    const int sg = (lane & 3) * 8;

    f32x4 acc[4][4] = {};
    for (int k0 = 0; k0 < D_; k0 += 32) {
#pragma unroll
        for (int c = 0; c < 2; ++c) {
            const int cc = w * 2 + c;
            const int row = cc * 16 + srow;
            gl_lds16(A + (size_t)(m0 + row) * D_ + k0 + sg, As + cc * 512);
            gl_lds16(Wm + (size_t)(n0 + row) * D_ + k0 + sg, Bs + cc * 512);
        }
        __syncthreads();
        short8 af[4], bf[4];
#pragma unroll
        for (int i = 0; i < 4; ++i) {
            af[i] = *(const short8*)(As + (wr * 64 + i * 16 + ln15) * 32 + quad * 8);
            bf[i] = *(const short8*)(Bs + (wc * 64 + i * 16 + ln15) * 32 + quad * 8);
        }
#pragma unroll
        for (int mt = 0; mt < 4; ++mt)
#pragma unroll
            for (int nt = 0; nt < 4; ++nt)
                acc[mt][nt] = __builtin_amdgcn_mfma_f32_16x16x32_bf16(
                    af[mt], bf[nt], acc[mt][nt], 0, 0, 0);
        __syncthreads();
    }
#pragma unroll
    for (int mt = 0; mt < 4; ++mt) {
#pragma unroll
        for (int r = 0; r < 4; ++r) {
            const int row = m0 + wr * 64 + mt * 16 + quad * 4 + r;
            const int bb = row >> 11, s = row & (S_ - 1);
#pragma unroll
            for (int nt = 0; nt < 4; ++nt) {
                const int col = n0 + wc * 64 + nt * 16 + ln15;
                const float vv = (acc[mt][nt][r] + bias[col]) * scale;
                const int h = col >> 6, dk = col & 63;
                outp[((((size_t)bb * H_ + h) * S_ + s) << 6) + dk] = f2bf(vv);
            }
        }
    }
}

// ---------------------------------------------------------------------------
// V [bh][s][dk] -> V^T [bh][dk][s]. Two layers of key permutation within each
// 64-key window so attn can form PV A-fragments in-register:
//   (1) kappa(sg,m): key order matching the permlane32-swap output of attn's
//       packed P registers; (2) XOR-swizzle of 8-key groups (pg = sg^(dk&7))
//       matching attn's async staging + swizzled ds_read.
// ---------------------------------------------------------------------------
__global__ __launch_bounds__(256) void vtrans(const ushort* __restrict__ Vs_,
                                              ushort* __restrict__ Vt_) {
    __shared__ ushort L[64 * 76];
    const int t = threadIdx.x;
    const int bh = blockIdx.y;
    const int s0 = blockIdx.x * 64;
    const ushort* src = Vs_ + (size_t)bh * S_ * DK_;
    ushort* dst = Vt_ + (size_t)bh * DK_ * S_;
    const int r = t >> 2, g = t & 3;
#pragma unroll
    for (int gg = 0; gg < 2; ++gg) {
        const int grp = g + gg * 4;
        const ushort8 v = *(const ushort8*)(src + (size_t)(s0 + r) * DK_ + grp * 8);
        *(ushort8*)(&L[r * 76 + grp * 8]) = v;
    }
    __syncthreads();
    const int dim = t >> 2;
    const int OFF[8] = {0, 1, 8, 9, 2, 3, 10, 11};
#pragma unroll
    for (int gg = 0; gg < 2; ++gg) {
        const int sg = g + gg * 4;          // logical storage group
        const int ks = sg >> 2, g2 = sg & 3;
        const int kb = ks * 32 + g2 * 4 + (g2 >> 1) * 8;
        ushort8 o;
#pragma unroll
        for (int j = 0; j < 8; ++j) o[j] = L[(kb + OFF[j]) * 76 + dim];
        const int pg = sg ^ (dim & 7);      // physical (swizzled) slot
        *(ushort8*)(dst + (size_t)dim * S_ + s0 + pg * 8) = o;
    }
}

// ---------------------------------------------------------------------------
// Output projection: fp32 out = A @ W^T + b, flat [M,D]
// ---------------------------------------------------------------------------
__global__ __launch_bounds__(256) void gemm_out(const ushort* __restrict__ A,
                                                const ushort* __restrict__ Wm,
                                                const float* __restrict__ bias,
                                                float* __restrict__ out) {
    __shared__ ushort As[128 * 32];
    __shared__ ushort Bs[128 * 32];
    const int t = threadIdx.x, w = t >> 6, lane = t & 63;
    const int ln15 = lane & 15, quad = lane >> 4;
    const int wr = w >> 1, wc = w & 1;
    const int n0 = blockIdx.x * 128, m0 = blockIdx.y * 128;
    const int srow = lane >> 2;
    const int sg = (lane & 3) * 8;

    f32x4 acc[4][4] = {};
    for (int k0 = 0; k0 < D_; k0 += 32) {
#pragma unroll
        for (int c = 0; c < 2; ++c) {
            const int cc = w * 2 + c;
            const int row = cc * 16 + srow;
            gl_lds16(A + (size_t)(m0 + row) * D_ + k0 + sg, As + cc * 512);
            gl_lds16(Wm + (size_t)(n0 + row) * D_ + k0 + sg, Bs + cc * 512);
        }
        __syncthreads();
        short8 af[4], bf[4];
#pragma unroll
        for (int i = 0; i < 4; ++i) {
            af[i] = *(const short8*)(As + (wr * 64 + i * 16 + ln15) * 32 + quad * 8);
            bf[i] = *(const short8*)(Bs + (wc * 64 + i * 16 + ln15) * 32 + quad * 8);
        }
#pragma unroll
        for (int mt = 0; mt < 4; ++mt)
#pragma unroll
            for (int nt = 0; nt < 4; ++nt)
                acc[mt][nt] = __builtin_amdgcn_mfma_f32_16x16x32_bf16(
                    af[mt], bf[nt], acc[mt][nt], 0, 0, 0);
        __syncthreads();
    }
#pragma unroll
    for (int mt = 0; mt < 4; ++mt) {
#pragma unroll
        for (int r = 0; r < 4; ++r) {
            const int row = m0 + wr * 64 + mt * 16 + quad * 4 + r;
#pragma unroll
            for (int nt = 0; nt < 4; ++nt) {
                const int col = n0 + wc * 64 + nt * 16 + ln15;
                out[(size_t)row * D_ + col] = acc[mt][nt][r] + bias[col];
            }
        }
    }
}

// ---------------------------------------------------------------------------
// Flash attention, no-LDS P path.
//   QK^T computed SWAPPED (mfma(K,Q)) so each lane holds S[key][qrow=ln15];
//   mask+exp2 in place, v_cvt_pk_bf16_f32 pairs, v_permlane32_swap x8 forms
//   the PV A-fragment entirely in registers (key permutation folded into
//   vtrans). mt-outer QK^T keeps only sc[4] live (reg pressure < 170 cap ->
//   no scratch spill; round-1's (256,4) 128-cap spilled: WRITE_SIZE 70 MB).
// ---------------------------------------------------------------------------
__global__ __launch_bounds__(256, 3) void attn_mfma(
    const ushort* __restrict__ Qd, const ushort* __restrict__ Kd,
    const ushort* __restrict__ Vtg, const unsigned long long* __restrict__ bits,
    ushort* __restrict__ ctx) {
    __shared__ ushort Ks[2][64 * 64];  // [key][dk], swizzled groups
    __shared__ ushort Vt[2][64 * 64];  // [dk][key], swizzled groups

    const int t = threadIdx.x, w = t >> 6, lane = t & 63;
    const int ln15 = lane & 15, quad = lane >> 4, q4 = quad * 4;
    const int lp = lane & 7, lr8 = lane >> 3;
    const int bh = blockIdx.y, b = bh >> 4, h = bh & 15;
    const int q0 = blockIdx.x * 128;

    const ushort* Qb = Qd + (size_t)bh * (S_ * DK_);
    const ushort* Kb = Kd + (size_t)bh * (S_ * DK_);
    const ushort* Vb = Vtg + (size_t)bh * (DK_ * S_);  // [dk][s] swizzled
    const unsigned long long* mbits = bits + (size_t)b * S_ * (S_ / 64);

    // mask word per qrow: qrow = q0 + w*32 + mt*16 + ln15 (2 words per lane)
    int mof[2];
#pragma unroll
    for (int mt = 0; mt < 2; ++mt)
        mof[mt] = (q0 + w * 32 + mt * 16 + ln15) * (S_ / 64);

    // Q fragments: loaded once, live in registers all kernel (B-operand now)
    short8 aq[2][2];  // [ks][mt]
#pragma unroll
    for (int ks = 0; ks < 2; ++ks)
#pragma unroll
        for (int mt = 0; mt < 2; ++mt)
            aq[ks][mt] = *(const short8*)(
                Qb + (size_t)(q0 + w * 32 + mt * 16 + ln15) * DK_ + ks * 32 + quad * 8);

    // stage K/V tile kt into buffer p (async; drained by the NEXT barrier)
    auto stageKV = [&](int kt, int p) {
        const int k0 = kt * 64;
#pragma unroll
        for (int c = 0; c < 2; ++c) {
            const int cc = w * 2 + c;
            const int row = cc * 8 + lr8;  // K: key row; V: dk row
            gl_lds16(Kb + (size_t)(k0 + row) * DK_ + (lp ^ lr8) * 8, &Ks[p][cc * 512]);
            gl_lds16(Vb + (size_t)row * S_ + k0 + lp * 8, &Vt[p][cc * 512]);
        }
    };

    stageKV(0, 0);
    unsigned long long mw[2];
    mw[0] = mbits[mof[0]];
    mw[1] = mbits[mof[1]];

    f32x4 O[2][4] = {};
    f32x4 lsum[2] = {};
    short8 vone;
#pragma unroll
    for (int j = 0; j < 8; ++j) vone[j] = (short)0x3F80;  // bf16(1.0)

    int p = 0;
    for (int kt = 0; kt < S_ / 64; ++kt) {
        __syncthreads();  // drains stageKV(kt); buffer p^1 now free
        if (kt < S_ / 64 - 1) stageKV(kt + 1, p ^ 1);

        // ---- S'^T = K (Q*QSCALE)^T then P = maskbit ? exp2 : 0, packed to
        // bf16 + permlane32-swapped into PV A-fragments. mt-outer so only
        // sc[4] (16 regs) is live at a time.
        short8 ap[2][2];  // [mt][ks]
#pragma unroll
        for (int mt = 0; mt < 2; ++mt) {
            f32x4 sc[4] = {};
#pragma unroll
            for (int ks = 0; ks < 2; ++ks) {
#pragma unroll
                for (int nt = 0; nt < 4; ++nt) {
                    const int row = nt * 16 + ln15;
                    const short8 bk = *(const short8*)(
                        &Ks[p][row * 64 + ((ks * 4 + quad) ^ (row & 7)) * 8]);
                    sc[nt] = __builtin_amdgcn_mfma_f32_16x16x32_bf16(
                        bk, aq[ks][mt], sc[nt], 0, 0, 0);
                }
            }
            unsigned pk[4][2];
#pragma unroll
            for (int nt = 0; nt < 4; ++nt) {
                float pv[4];
#pragma unroll
                for (int r = 0; r < 4; ++r) {
                    const float e = __builtin_amdgcn_exp2f(sc[nt][r]);
                    pv[r] = ((mw[mt] >> (nt * 16 + q4 + r)) & 1ull) ? e : 0.0f;
                }
                pk[nt][0] = cvt_pk_bf16(pv[0], pv[1]);
                pk[nt][1] = cvt_pk_bf16(pv[2], pv[3]);
            }
            // after swap: pk[2ks][h] = A'-word, pk[2ks+1][h] = B'-word
            pl32_swap(pk[0][0], pk[1][0]);
            pl32_swap(pk[0][1], pk[1][1]);
            pl32_swap(pk[2][0], pk[3][0]);
            pl32_swap(pk[2][1], pk[3][1]);
            ap[mt][0] = mk8(pk[0][0], pk[1][0], pk[0][1], pk[1][1]);
            ap[mt][1] = mk8(pk[2][0], pk[3][0], pk[2][1], pk[3][1]);
        }

        // prefetch mask for kt+1
        if (kt < S_ / 64 - 1) {
            mw[0] = mbits[mof[0] + kt + 1];
            mw[1] = mbits[mof[1] + kt + 1];
        }

        // ---- O += P V^T ; lsum += P @ ones
#pragma unroll
        for (int ks = 0; ks < 2; ++ks) {
            short8 bv4[4];
#pragma unroll
            for (int nt = 0; nt < 4; ++nt) {
                const int dim = nt * 16 + ln15;
                bv4[nt] = *(const short8*)(&Vt[p][dim * 64 + ((ks * 4 + quad) ^ (dim & 7)) * 8]);
            }
#pragma unroll
            for (int mt = 0; mt < 2; ++mt) {
#pragma unroll
                for (int nt = 0; nt < 4; ++nt)
                    O[mt][nt] = __builtin_amdgcn_mfma_f32_16x16x32_bf16(
                        ap[mt][ks], bv4[nt], O[mt][nt], 0, 0, 0);
                lsum[mt] = __builtin_amdgcn_mfma_f32_16x16x32_bf16(
                    ap[mt][ks], vone, lsum[mt], 0, 0, 0);
            }
        }
        p ^= 1;
    }

    // finalize: ctx[b][s][h*64+dim] = O / lsum (bf16, feeds out-proj)
#pragma unroll
    for (int mt = 0; mt < 2; ++mt) {
#pragma unroll
        for (int r = 0; r < 4; ++r) {
            const int qg = q0 + w * 32 + mt * 16 + quad * 4 + r;
            const float inv = __builtin_amdgcn_rcpf(lsum[mt][r]);
#pragma unroll
            for (int nt = 0; nt < 4; ++nt) {
                const int dim = nt * 16 + ln15;
                ctx[((size_t)b * S_ + qg) * D_ + h * DK_ + dim] = f2bf(O[mt][nt][r] * inv);
            }
        }
    }
}

// ---------------------------------------------------------------------------
extern "C" void kernel_launch(void* const* d_in, const int* in_sizes, int n_in,
                              void* d_out, int out_size, void* d_ws, size_t ws_size,
                              hipStream_t stream) {
    (void)in_sizes; (void)n_in; (void)out_size; (void)ws_size;
    const float* query = (const float*)d_in[0];
    const float* key_  = (const float*)d_in[1];
    const float* value = (const float*)d_in[2];
    const int*   mask  = (const int*)d_in[3];
    const float* Wq = (const float*)d_in[4];
    const float* bq = (const float*)d_in[5];
    const float* Wk = (const float*)d_in[6];
    const float* bk = (const float*)d_in[7];
    const float* Wv = (const float*)d_in[8];
    const float* bv = (const float*)d_in[9];
    const float* Wo = (const float*)d_in[10];
    const float* bo = (const float*)d_in[11];
    float* out = (float*)d_out;

    const size_t nX = (size_t)B_ * S_ * D_;  // 8,388,608
    const size_t nW = (size_t)D_ * D_;       // 1,048,576
    ushort* qkv = (ushort*)d_ws;       // 3*nX bf16 (q,k,v casts)
    ushort* Wb  = qkv + 3 * nX;        // 4*nW bf16
    ushort* Qd  = Wb + 4 * nW;
    ushort* Kd  = Qd + nX;
    ushort* Vd  = Kd + nX;             // standard [B,H,S,DK]
    unsigned long long* bits = (unsigned long long*)(Vd + nX);  // 2 MB
    ushort* ctx = qkv;                 // q-cast region, dead after gemm_proj
    ushort* VtT = qkv + 2 * nX;        // v-cast region, dead after gemm_proj

    cast_all<<<14336, 256, 0, stream>>>(query, key_, value, Wq, Wk, Wv, Wo, qkv, Wb);
    mask_bits_kernel<<<B_ * S_ * S_ / 256, 256, 0, stream>>>(mask, bits);

    dim3 gp(D_ / 128, (B_ * S_) / 128, 3);  // (8, 64, 3)
    gemm_proj<<<gp, 256, 0, stream>>>(qkv, qkv + nX, qkv + 2 * nX, Wb,
                                      bq, bk, bv, Qd, Kd, Vd);

    dim3 gv(S_ / 64, B_ * H_);  // (32, 64)
    vtrans<<<gv, 256, 0, stream>>>(Vd, VtT);

    dim3 ga(S_ / 128, B_ * H_);  // (16, 64)
    attn_mfma<<<ga, 256, 0, stream>>>(Qd, Kd, VtT, bits, ctx);

    dim3 go(D_ / 128, (B_ * S_) / 128);  // (8, 64)
    gemm_out<<<go, 256, 0, stream>>>(ctx, Wb + 3 * nW, bo, out);
}

// Round 3
// 434.564 us; speedup vs baseline: 1.3711x; 1.0505x over previous
//
#include <hip/hip_runtime.h>

#define B_  4
#define S_  2048
#define D_  1024
#define H_  16
#define DK_ 64

typedef unsigned short ushort;
typedef __attribute__((ext_vector_type(8))) short short8;
typedef __attribute__((ext_vector_type(8))) unsigned short ushort8;
typedef __attribute__((ext_vector_type(4))) float f32x4;

// scores use exp2: fold 0.125 * log2(e) into Q at projection time
#define QSCALE 0.18033688011112042f

__device__ __forceinline__ ushort f2bf(float f) {  // RNE
    unsigned int u = __float_as_uint(f);
    u += 0x7fffu + ((u >> 16) & 1u);
    return (ushort)(u >> 16);
}

__device__ __forceinline__ unsigned cvt_pk_bf16(float lo, float hi) {
    unsigned r;
    asm("v_cvt_pk_bf16_f32 %0, %1, %2" : "=v"(r) : "v"(lo), "v"(hi));
    return r;
}
// swaps a[32:63] <-> b[0:31]
__device__ __forceinline__ void pl32_swap(unsigned& a, unsigned& b) {
    asm("v_permlane32_swap_b32 %0, %1" : "+v"(a), "+v"(b));
}
__device__ __forceinline__ short8 mk8(unsigned a, unsigned b, unsigned c,
                                      unsigned d) {
    union { unsigned u[4]; short8 s; } x;
    x.u[0] = a; x.u[1] = b; x.u[2] = c; x.u[3] = d;
    return x.s;
}

__device__ __forceinline__ void gl_lds16(const ushort* g, ushort* ldsbase) {
    __builtin_amdgcn_global_load_lds(
        (const __attribute__((address_space(1))) void*)g,
        (__attribute__((address_space(3))) void*)ldsbase, 16, 0, 0);
}

// ---------------------------------------------------------------------------
// Cast q,k,v + Wq,Wk,Wv,Wo to bf16 in one launch.
// ---------------------------------------------------------------------------
__global__ __launch_bounds__(256) void cast_all(
    const float* __restrict__ q, const float* __restrict__ k,
    const float* __restrict__ v, const float* __restrict__ Wq,
    const float* __restrict__ Wk, const float* __restrict__ Wv,
    const float* __restrict__ Wo, ushort* __restrict__ qkv_dst,
    ushort* __restrict__ w_dst) {
    const int bid = blockIdx.x;
    const float* src;
    ushort* dst;
    int lb;
    if (bid < 12288) {
        const int s = bid >> 12;
        lb = bid & 4095;
        src = (s == 0) ? q : (s == 1) ? k : v;
        dst = qkv_dst + (size_t)s * (B_ * S_ * D_);
    } else {
        const int wi = (bid - 12288) >> 9;
        lb = (bid - 12288) & 511;
        src = (wi == 0) ? Wq : (wi == 1) ? Wk : (wi == 2) ? Wv : Wo;
        dst = w_dst + (size_t)wi * (D_ * D_);
    }
    const int i = lb * 2048 + threadIdx.x * 8;
    const float4 a = *(const float4*)(src + i);
    const float4 b = *(const float4*)(src + i + 4);
    ushort8 r;
    r[0] = f2bf(a.x); r[1] = f2bf(a.y); r[2] = f2bf(a.z); r[3] = f2bf(a.w);
    r[4] = f2bf(b.x); r[5] = f2bf(b.y); r[6] = f2bf(b.z); r[7] = f2bf(b.w);
    *(ushort8*)(dst + i) = r;
}

// ---------------------------------------------------------------------------
// Mask pack: per 64-key window, lane L reads key kappa(L) so that __ballot
// directly yields the quad-chunked word: bit (quad*16 + nt*4 + r) = mask at
// key (nt*16 + quad*4 + r). Layout mpk[b][kt][q] (ull) -> attn reads ONE
// ushort per (qrow, tile): [b][kt][q][quad], 128B/wave fully coalesced.
// ---------------------------------------------------------------------------
__global__ __launch_bounds__(256) void mask_pack(
    const int* __restrict__ m, unsigned long long* __restrict__ mpk) {
    const size_t idx = (size_t)blockIdx.x * 256 + threadIdx.x;
    const int lane = threadIdx.x & 63;
    const size_t wbase = idx & ~(size_t)63;  // element base of this window
    const int kap = (((lane >> 2) & 3) << 4) | ((lane >> 4) << 2) | (lane & 3);
    const unsigned long long W = __ballot(m[wbase + kap] != 0);
    if (lane == 0) {
        const size_t widx = wbase >> 6;
        const int kt = (int)(widx & 31);
        const int qq = (int)((widx >> 5) & 2047);
        const int bb = (int)(widx >> 16);
        mpk[((size_t)bb * 32 + kt) * 2048 + qq] = W;
    }
}

// ---------------------------------------------------------------------------
// Fused Q/K/V projection (blockIdx.z selects). out = (A @ W^T + b)*scale.
// z=0/1: bf16 scatter to [B,H,S,DK]. z=2: writes V^T [bh][dk][s] directly
// with the kappa+XOR key permutation folded in (replaces the vtrans kernel).
// ---------------------------------------------------------------------------
__global__ __launch_bounds__(256) void gemm_proj(
    const ushort* __restrict__ qb, const ushort* __restrict__ kb,
    const ushort* __restrict__ vb, const ushort* __restrict__ Wb,
    const float* __restrict__ bq, const float* __restrict__ bk,
    const float* __restrict__ bv, ushort* __restrict__ Qd,
    ushort* __restrict__ Kd, ushort* __restrict__ Vt) {
    const int z = blockIdx.z;
    const ushort* A  = (z == 0) ? qb : (z == 1) ? kb : vb;
    const ushort* Wm = Wb + (size_t)z * (D_ * D_);
    const float* bias = (z == 0) ? bq : (z == 1) ? bk : bv;
    const float scale = (z == 0) ? QSCALE : 1.0f;

    __shared__ ushort As[128 * 32];
    __shared__ ushort Bs[128 * 32];
    const int t = threadIdx.x, w = t >> 6, lane = t & 63;
    const int ln15 = lane & 15, quad = lane >> 4;
    const int wr = w >> 1, wc = w & 1;
    const int n0 = blockIdx.x * 128, m0 = blockIdx.y * 128;
    const int srow = lane >> 2;
    const int sg = (lane & 3) * 8;

    f32x4 acc[4][4] = {};
    for (int k0 = 0; k0 < D_; k0 += 32) {
#pragma unroll
        for (int c = 0; c < 2; ++c) {
            const int cc = w * 2 + c;
            const int row = cc * 16 + srow;
            gl_lds16(A + (size_t)(m0 + row) * D_ + k0 + sg, As + cc * 512);
            gl_lds16(Wm + (size_t)(n0 + row) * D_ + k0 + sg, Bs + cc * 512);
        }
        __syncthreads();
        short8 af[4], bf[4];
#pragma unroll
        for (int i = 0; i < 4; ++i) {
            af[i] = *(const short8*)(As + (wr * 64 + i * 16 + ln15) * 32 + quad * 8);
            bf[i] = *(const short8*)(Bs + (wc * 64 + i * 16 + ln15) * 32 + quad * 8);
        }
#pragma unroll
        for (int mt = 0; mt < 4; ++mt)
#pragma unroll
            for (int nt = 0; nt < 4; ++nt)
                acc[mt][nt] = __builtin_amdgcn_mfma_f32_16x16x32_bf16(
                    af[mt], bf[nt], acc[mt][nt], 0, 0, 0);
        __syncthreads();
    }
#pragma unroll
    for (int mt = 0; mt < 4; ++mt) {
#pragma unroll
        for (int r = 0; r < 4; ++r) {
            const int row = m0 + wr * 64 + mt * 16 + quad * 4 + r;
            const int bb = row >> 11, s = row & (S_ - 1);
            if (z == 2) {
                // inverse kappa: token-in-window m -> sg*8+j
                const int mm = s & 63, s0w = s & ~63;
                const int g2 = ((mm >> 2) & 1) | ((mm >> 3) & 2);
                const int sgi = ((mm >> 5) & 1) * 4 + g2;
                const int jj = (mm & 1) | ((mm >> 2) & 2) | ((mm << 1) & 4);
#pragma unroll
                for (int nt = 0; nt < 4; ++nt) {
                    const int col = n0 + wc * 64 + nt * 16 + ln15;
                    const float vv = acc[mt][nt][r] + bias[col];
                    const int h = col >> 6, dk = col & 63;
                    const int phys = ((sgi ^ (dk & 7)) << 3) | jj;
                    Vt[((((size_t)bb * H_ + h) * DK_ + dk) << 11) + s0w + phys] =
                        f2bf(vv);
                }
            } else {
#pragma unroll
                for (int nt = 0; nt < 4; ++nt) {
                    const int col = n0 + wc * 64 + nt * 16 + ln15;
                    const float vv = (acc[mt][nt][r] + bias[col]) * scale;
                    const int h = col >> 6, dk = col & 63;
                    ushort* outp = (z == 0) ? Qd : Kd;
                    outp[((((size_t)bb * H_ + h) * S_ + s) << 6) + dk] = f2bf(vv);
                }
            }
        }
    }
}

// ---------------------------------------------------------------------------
// Output projection: fp32 out = A @ W^T + b, flat [M,D]
// ---------------------------------------------------------------------------
__global__ __launch_bounds__(256) void gemm_out(const ushort* __restrict__ A,
                                                const ushort* __restrict__ Wm,
                                                const float* __restrict__ bias,
                                                float* __restrict__ out) {
    __shared__ ushort As[128 * 32];
    __shared__ ushort Bs[128 * 32];
    const int t = threadIdx.x, w = t >> 6, lane = t & 63;
    const int ln15 = lane & 15, quad = lane >> 4;
    const int wr = w >> 1, wc = w & 1;
    const int n0 = blockIdx.x * 128, m0 = blockIdx.y * 128;
    const int srow = lane >> 2;
    const int sg = (lane & 3) * 8;

    f32x4 acc[4][4] = {};
    for (int k0 = 0; k0 < D_; k0 += 32) {
#pragma unroll
        for (int c = 0; c < 2; ++c) {
            const int cc = w * 2 + c;
            const int row = cc * 16 + srow;
            gl_lds16(A + (size_t)(m0 + row) * D_ + k0 + sg, As + cc * 512);
            gl_lds16(Wm + (size_t)(n0 + row) * D_ + k0 + sg, Bs + cc * 512);
        }
        __syncthreads();
        short8 af[4], bf[4];
#pragma unroll
        for (int i = 0; i < 4; ++i) {
            af[i] = *(const short8*)(As + (wr * 64 + i * 16 + ln15) * 32 + quad * 8);
            bf[i] = *(const short8*)(Bs + (wc * 64 + i * 16 + ln15) * 32 + quad * 8);
        }
#pragma unroll
        for (int mt = 0; mt < 4; ++mt)
#pragma unroll
            for (int nt = 0; nt < 4; ++nt)
                acc[mt][nt] = __builtin_amdgcn_mfma_f32_16x16x32_bf16(
                    af[mt], bf[nt], acc[mt][nt], 0, 0, 0);
        __syncthreads();
    }
#pragma unroll
    for (int mt = 0; mt < 4; ++mt) {
#pragma unroll
        for (int r = 0; r < 4; ++r) {
            const int row = m0 + wr * 64 + mt * 16 + quad * 4 + r;
#pragma unroll
            for (int nt = 0; nt < 4; ++nt) {
                const int col = n0 + wc * 64 + nt * 16 + ln15;
                out[(size_t)row * D_ + col] = acc[mt][nt][r] + bias[col];
            }
        }
    }
}

// ---------------------------------------------------------------------------
// Flash attention, no-LDS P path. (256,4): total VGPR+AGPR capped at 128 ->
// 4 blocks/CU (live set ~110 after mt-outer + ushort masks). Mask applied
// with 2 VALU ops/elem (shl/ashr sign-fill + and on float bits). s_setprio
// around both MFMA clusters.
// ---------------------------------------------------------------------------
__global__ __launch_bounds__(256, 4) void attn_mfma(
    const ushort* __restrict__ Qd, const ushort* __restrict__ Kd,
    const ushort* __restrict__ Vtg, const ushort* __restrict__ mpk,
    ushort* __restrict__ ctx) {
    __shared__ ushort Ks[2][64 * 64];  // [key][dk], swizzled groups
    __shared__ ushort Vt[2][64 * 64];  // [dk][key], swizzled groups

    const int t = threadIdx.x, w = t >> 6, lane = t & 63;
    const int ln15 = lane & 15, quad = lane >> 4;
    const int lp = lane & 7, lr8 = lane >> 3;
    const int bh = blockIdx.y, b = bh >> 4, h = bh & 15;
    const int q0 = blockIdx.x * 128;

    const ushort* Qb = Qd + (size_t)bh * (S_ * DK_);
    const ushort* Kb = Kd + (size_t)bh * (S_ * DK_);
    const ushort* Vb = Vtg + (size_t)bh * (DK_ * S_);  // [dk][s] swizzled
    // packed mask: ushort at ((b*32 + kt)*2048 + qrow)*4 + quad
    const ushort* mb = mpk + (size_t)b * 32 * 2048 * 4;

    int mof[2];
#pragma unroll
    for (int mt = 0; mt < 2; ++mt)
        mof[mt] = ((q0 + w * 32 + mt * 16 + ln15) << 2) + quad;

    // Q fragments: loaded once, live in registers all kernel (B-operand)
    short8 aq[2][2];  // [ks][mt]
#pragma unroll
    for (int ks = 0; ks < 2; ++ks)
#pragma unroll
        for (int mt = 0; mt < 2; ++mt)
            aq[ks][mt] = *(const short8*)(
                Qb + (size_t)(q0 + w * 32 + mt * 16 + ln15) * DK_ + ks * 32 + quad * 8);

    // stage K/V tile kt into buffer p (async; drained by the NEXT barrier)
    auto stageKV = [&](int kt, int p) {
        const int k0 = kt * 64;
#pragma unroll
        for (int c = 0; c < 2; ++c) {
            const int cc = w * 2 + c;
            const int row = cc * 8 + lr8;  // K: key row; V: dk row
            gl_lds16(Kb + (size_t)(k0 + row) * DK_ + (lp ^ lr8) * 8, &Ks[p][cc * 512]);
            gl_lds16(Vb + (size_t)row * S_ + k0 + lp * 8, &Vt[p][cc * 512]);
        }
    };

    stageKV(0, 0);
    unsigned mv[2];
    mv[0] = mb[mof[0]];
    mv[1] = mb[mof[1]];

    f32x4 O[2][4] = {};
    f32x4 lsum[2] = {};
    short8 vone;
#pragma unroll
    for (int j = 0; j < 8; ++j) vone[j] = (short)0x3F80;  // bf16(1.0)

    int p = 0;
    for (int kt = 0; kt < S_ / 64; ++kt) {
        __syncthreads();  // drains stageKV(kt); buffer p^1 now free
        if (kt < S_ / 64 - 1) stageKV(kt + 1, p ^ 1);

        // ---- S'^T = K (Q*QSCALE)^T then P = maskbit ? exp2 : 0, packed to
        // bf16 + permlane32-swapped into PV A-fragments. mt-outer: only sc[4]
        // live at a time.
        short8 ap[2][2];  // [mt][ks]
#pragma unroll
        for (int mt = 0; mt < 2; ++mt) {
            f32x4 sc[4] = {};
            __builtin_amdgcn_s_setprio(1);
#pragma unroll
            for (int ks = 0; ks < 2; ++ks) {
#pragma unroll
                for (int nt = 0; nt < 4; ++nt) {
                    const int row = nt * 16 + ln15;
                    const short8 bk = *(const short8*)(
                        &Ks[p][row * 64 + ((ks * 4 + quad) ^ (row & 7)) * 8]);
                    sc[nt] = __builtin_amdgcn_mfma_f32_16x16x32_bf16(
                        bk, aq[ks][mt], sc[nt], 0, 0, 0);
                }
            }
            __builtin_amdgcn_s_setprio(0);
            unsigned pk[4][2];
#pragma unroll
            for (int nt = 0; nt < 4; ++nt) {
                float pv[4];
#pragma unroll
                for (int r = 0; r < 4; ++r) {
                    const float e = __builtin_amdgcn_exp2f(sc[nt][r]);
                    // bit nt*4+r of mv -> 0 / 0xFFFFFFFF, AND with float bits
                    const unsigned msk =
                        (unsigned)((int)(mv[mt] << (31 - (nt * 4 + r))) >> 31);
                    pv[r] = __uint_as_float(__float_as_uint(e) & msk);
                }
                pk[nt][0] = cvt_pk_bf16(pv[0], pv[1]);
                pk[nt][1] = cvt_pk_bf16(pv[2], pv[3]);
            }
            // after swap: pk[2ks][h] = A'-word, pk[2ks+1][h] = B'-word
            pl32_swap(pk[0][0], pk[1][0]);
            pl32_swap(pk[0][1], pk[1][1]);
            pl32_swap(pk[2][0], pk[3][0]);
            pl32_swap(pk[2][1], pk[3][1]);
            ap[mt][0] = mk8(pk[0][0], pk[1][0], pk[0][1], pk[1][1]);
            ap[mt][1] = mk8(pk[2][0], pk[3][0], pk[2][1], pk[3][1]);
        }

        // prefetch mask for kt+1
        if (kt < S_ / 64 - 1) {
            mv[0] = mb[(kt + 1) * 8192 + mof[0]];
            mv[1] = mb[(kt + 1) * 8192 + mof[1]];
        }

        // ---- O += P V^T ; lsum += P @ ones
#pragma unroll
        for (int ks = 0; ks < 2; ++ks) {
            short8 bv4[4];
#pragma unroll
            for (int nt = 0; nt < 4; ++nt) {
                const int dim = nt * 16 + ln15;
                bv4[nt] = *(const short8*)(&Vt[p][dim * 64 + ((ks * 4 + quad) ^ (dim & 7)) * 8]);
            }
            __builtin_amdgcn_s_setprio(1);
#pragma unroll
            for (int mt = 0; mt < 2; ++mt) {
#pragma unroll
                for (int nt = 0; nt < 4; ++nt)
                    O[mt][nt] = __builtin_amdgcn_mfma_f32_16x16x32_bf16(
                        ap[mt][ks], bv4[nt], O[mt][nt], 0, 0, 0);
                lsum[mt] = __builtin_amdgcn_mfma_f32_16x16x32_bf16(
                    ap[mt][ks], vone, lsum[mt], 0, 0, 0);
            }
            __builtin_amdgcn_s_setprio(0);
        }
        p ^= 1;
    }

    // finalize: ctx[b][s][h*64+dim] = O / lsum (bf16, feeds out-proj)
#pragma unroll
    for (int mt = 0; mt < 2; ++mt) {
#pragma unroll
        for (int r = 0; r < 4; ++r) {
            const int qg = q0 + w * 32 + mt * 16 + quad * 4 + r;
            const float inv = __builtin_amdgcn_rcpf(lsum[mt][r]);
#pragma unroll
            for (int nt = 0; nt < 4; ++nt) {
                const int dim = nt * 16 + ln15;
                ctx[((size_t)b * S_ + qg) * D_ + h * DK_ + dim] = f2bf(O[mt][nt][r] * inv);
            }
        }
    }
}

// ---------------------------------------------------------------------------
extern "C" void kernel_launch(void* const* d_in, const int* in_sizes, int n_in,
                              void* d_out, int out_size, void* d_ws, size_t ws_size,
                              hipStream_t stream) {
    (void)in_sizes; (void)n_in; (void)out_size; (void)ws_size;
    const float* query = (const float*)d_in[0];
    const float* key_  = (const float*)d_in[1];
    const float* value = (const float*)d_in[2];
    const int*   mask  = (const int*)d_in[3];
    const float* Wq = (const float*)d_in[4];
    const float* bq = (const float*)d_in[5];
    const float* Wk = (const float*)d_in[6];
    const float* bk = (const float*)d_in[7];
    const float* Wv = (const float*)d_in[8];
    const float* bv = (const float*)d_in[9];
    const float* Wo = (const float*)d_in[10];
    const float* bo = (const float*)d_in[11];
    float* out = (float*)d_out;

    const size_t nX = (size_t)B_ * S_ * D_;  // 8,388,608
    const size_t nW = (size_t)D_ * D_;       // 1,048,576
    ushort* qkv = (ushort*)d_ws;       // 3*nX bf16 (q,k,v casts)
    ushort* Wb  = qkv + 3 * nX;        // 4*nW bf16
    ushort* Qd  = Wb + 4 * nW;
    ushort* Kd  = Qd + nX;
    ushort* Vt  = Kd + nX;             // V^T [bh][dk][s], kappa+XOR permuted
    unsigned long long* mpk = (unsigned long long*)(Vt + nX);  // 2 MB
    ushort* ctx = qkv;                 // q-cast region, dead after gemm_proj

    cast_all<<<14336, 256, 0, stream>>>(query, key_, value, Wq, Wk, Wv, Wo, qkv, Wb);
    mask_pack<<<B_ * S_ * S_ / 256, 256, 0, stream>>>(mask, mpk);

    dim3 gp(D_ / 128, (B_ * S_) / 128, 3);  // (8, 64, 3)
    gemm_proj<<<gp, 256, 0, stream>>>(qkv, qkv + nX, qkv + 2 * nX, Wb,
                                      bq, bk, bv, Qd, Kd, Vt);

    dim3 ga(S_ / 128, B_ * H_);  // (16, 64)
    attn_mfma<<<ga, 256, 0, stream>>>(Qd, Kd, Vt, (const ushort*)mpk, ctx);

    dim3 go(D_ / 128, (B_ * S_) / 128);  // (8, 64)
    gemm_out<<<go, 256, 0, stream>>>(ctx, Wb + 3 * nW, bo, out);
}

// Round 5
// 424.944 us; speedup vs baseline: 1.4022x; 1.0226x over previous
//
#include <hip/hip_runtime.h>

#define B_  4
#define S_  2048
#define D_  1024
#define H_  16
#define DK_ 64

typedef unsigned short ushort;
typedef __attribute__((ext_vector_type(8))) short short8;
typedef __attribute__((ext_vector_type(8))) unsigned short ushort8;
typedef __attribute__((ext_vector_type(4))) float f32x4;

// scores use exp2: fold 0.125 * log2(e) into Q at projection time
#define QSCALE 0.18033688011112042f

__device__ __forceinline__ ushort f2bf(float f) {  // RNE
    unsigned int u = __float_as_uint(f);
    u += 0x7fffu + ((u >> 16) & 1u);
    return (ushort)(u >> 16);
}

__device__ __forceinline__ unsigned cvt_pk_bf16(float lo, float hi) {
    unsigned r;
    asm("v_cvt_pk_bf16_f32 %0, %1, %2" : "=v"(r) : "v"(lo), "v"(hi));
    return r;
}
// swaps a[32:63] <-> b[0:31]
__device__ __forceinline__ void pl32_swap(unsigned& a, unsigned& b) {
    asm("v_permlane32_swap_b32 %0, %1" : "+v"(a), "+v"(b));
}
__device__ __forceinline__ short8 mk8(unsigned a, unsigned b, unsigned c,
                                      unsigned d) {
    union { unsigned u[4]; short8 s; } x;
    x.u[0] = a; x.u[1] = b; x.u[2] = c; x.u[3] = d;
    return x.s;
}

__device__ __forceinline__ void gl_lds16(const ushort* g, ushort* ldsbase) {
    __builtin_amdgcn_global_load_lds(
        (const __attribute__((address_space(1))) void*)g,
        (__attribute__((address_space(3))) void*)ldsbase, 16, 0, 0);
}

// ---------------------------------------------------------------------------
// Merged: cast q,k,v + Wq,Wk,Wv,Wo to bf16 (blocks 0..14335) AND mask pack
// (blocks 14336..79871 — 65536 mask blocks, B*S*S/256). Mask pack: per
// 64-key window, lane L reads key kappa(L) so __ballot directly yields the
// quad-chunked word: bit (quad*16 + nt*4 + r) = mask at key
// (nt*16 + quad*4 + r). Layout mpk[b][kt][q] (ull) -> attn reads ONE
// ushort: [b][kt][q][quad].
// ---------------------------------------------------------------------------
__global__ __launch_bounds__(256) void cast_mask(
    const float* __restrict__ q, const float* __restrict__ k,
    const float* __restrict__ v, const float* __restrict__ Wq,
    const float* __restrict__ Wk, const float* __restrict__ Wv,
    const float* __restrict__ Wo, const int* __restrict__ m,
    ushort* __restrict__ qkv_dst, ushort* __restrict__ w_dst,
    unsigned long long* __restrict__ mpk) {
    int bid = blockIdx.x;
    if (bid >= 14336) {  // ---- mask pack path (65536 blocks)
        bid -= 14336;
        const size_t idx = (size_t)bid * 256 + threadIdx.x;
        const int lane = threadIdx.x & 63;
        const size_t wbase = idx & ~(size_t)63;
        const int kap = (((lane >> 2) & 3) << 4) | ((lane >> 4) << 2) | (lane & 3);
        const unsigned long long W = __ballot(m[wbase + kap] != 0);
        if (lane == 0) {
            const size_t widx = wbase >> 6;
            const int kt = (int)(widx & 31);
            const int qq = (int)((widx >> 5) & 2047);
            const int bb = (int)(widx >> 16);
            mpk[((size_t)bb * 32 + kt) * 2048 + qq] = W;
        }
        return;
    }
    const float* src;
    ushort* dst;
    int lb;
    if (bid < 12288) {
        const int s = bid >> 12;
        lb = bid & 4095;
        src = (s == 0) ? q : (s == 1) ? k : v;
        dst = qkv_dst + (size_t)s * (B_ * S_ * D_);
    } else {
        const int wi = (bid - 12288) >> 9;
        lb = (bid - 12288) & 511;
        src = (wi == 0) ? Wq : (wi == 1) ? Wk : (wi == 2) ? Wv : Wo;
        dst = w_dst + (size_t)wi * (D_ * D_);
    }
    const int i = lb * 2048 + threadIdx.x * 8;
    const float4 a = *(const float4*)(src + i);
    const float4 b = *(const float4*)(src + i + 4);
    ushort8 r;
    r[0] = f2bf(a.x); r[1] = f2bf(a.y); r[2] = f2bf(a.z); r[3] = f2bf(a.w);
    r[4] = f2bf(b.x); r[5] = f2bf(b.y); r[6] = f2bf(b.z); r[7] = f2bf(b.w);
    *(ushort8*)(dst + i) = r;
}

// ---------------------------------------------------------------------------
// Fused Q/K/V projection (blockIdx.z selects). out = (A @ W^T + b)*scale.
// z=0/1: bf16 scatter to [B,H,S,DK]. z=2: writes V^T [bh][dk][s] directly
// with the kappa+XOR key permutation folded in (replaces the vtrans kernel).
// ---------------------------------------------------------------------------
__global__ __launch_bounds__(256) void gemm_proj(
    const ushort* __restrict__ qb, const ushort* __restrict__ kb,
    const ushort* __restrict__ vb, const ushort* __restrict__ Wb,
    const float* __restrict__ bq, const float* __restrict__ bk,
    const float* __restrict__ bv, ushort* __restrict__ Qd,
    ushort* __restrict__ Kd, ushort* __restrict__ Vt) {
    const int z = blockIdx.z;
    const ushort* A  = (z == 0) ? qb : (z == 1) ? kb : vb;
    const ushort* Wm = Wb + (size_t)z * (D_ * D_);
    const float* bias = (z == 0) ? bq : (z == 1) ? bk : bv;
    const float scale = (z == 0) ? QSCALE : 1.0f;

    __shared__ ushort As[128 * 32];
    __shared__ ushort Bs[128 * 32];
    const int t = threadIdx.x, w = t >> 6, lane = t & 63;
    const int ln15 = lane & 15, quad = lane >> 4;
    const int wr = w >> 1, wc = w & 1;
    const int n0 = blockIdx.x * 128, m0 = blockIdx.y * 128;
    const int srow = lane >> 2;
    const int sg = (lane & 3) * 8;

    f32x4 acc[4][4] = {};
    for (int k0 = 0; k0 < D_; k0 += 32) {
#pragma unroll
        for (int c = 0; c < 2; ++c) {
            const int cc = w * 2 + c;
            const int row = cc * 16 + srow;
            gl_lds16(A + (size_t)(m0 + row) * D_ + k0 + sg, As + cc * 512);
            gl_lds16(Wm + (size_t)(n0 + row) * D_ + k0 + sg, Bs + cc * 512);
        }
        __syncthreads();
        short8 af[4], bf[4];
#pragma unroll
        for (int i = 0; i < 4; ++i) {
            af[i] = *(const short8*)(As + (wr * 64 + i * 16 + ln15) * 32 + quad * 8);
            bf[i] = *(const short8*)(Bs + (wc * 64 + i * 16 + ln15) * 32 + quad * 8);
        }
#pragma unroll
        for (int mt = 0; mt < 4; ++mt)
#pragma unroll
            for (int nt = 0; nt < 4; ++nt)
                acc[mt][nt] = __builtin_amdgcn_mfma_f32_16x16x32_bf16(
                    af[mt], bf[nt], acc[mt][nt], 0, 0, 0);
        __syncthreads();
    }
#pragma unroll
    for (int mt = 0; mt < 4; ++mt) {
#pragma unroll
        for (int r = 0; r < 4; ++r) {
            const int row = m0 + wr * 64 + mt * 16 + quad * 4 + r;
            const int bb = row >> 11, s = row & (S_ - 1);
            if (z == 2) {
                // inverse kappa: token-in-window m -> sg*8+j
                const int mm = s & 63, s0w = s & ~63;
                const int g2 = ((mm >> 2) & 1) | ((mm >> 3) & 2);
                const int sgi = ((mm >> 5) & 1) * 4 + g2;
                const int jj = (mm & 1) | ((mm >> 2) & 2) | ((mm << 1) & 4);
#pragma unroll
                for (int nt = 0; nt < 4; ++nt) {
                    const int col = n0 + wc * 64 + nt * 16 + ln15;
                    const float vv = acc[mt][nt][r] + bias[col];
                    const int h = col >> 6, dk = col & 63;
                    const int phys = ((sgi ^ (dk & 7)) << 3) | jj;
                    Vt[((((size_t)bb * H_ + h) * DK_ + dk) << 11) + s0w + phys] =
                        f2bf(vv);
                }
            } else {
#pragma unroll
                for (int nt = 0; nt < 4; ++nt) {
                    const int col = n0 + wc * 64 + nt * 16 + ln15;
                    const float vv = (acc[mt][nt][r] + bias[col]) * scale;
                    const int h = col >> 6, dk = col & 63;
                    ushort* outp = (z == 0) ? Qd : Kd;
                    outp[((((size_t)bb * H_ + h) * S_ + s) << 6) + dk] = f2bf(vv);
                }
            }
        }
    }
}

// ---------------------------------------------------------------------------
// Output projection: fp32 out = A @ W^T + b, flat [M,D]
// ---------------------------------------------------------------------------
__global__ __launch_bounds__(256) void gemm_out(const ushort* __restrict__ A,
                                                const ushort* __restrict__ Wm,
                                                const float* __restrict__ bias,
                                                float* __restrict__ out) {
    __shared__ ushort As[128 * 32];
    __shared__ ushort Bs[128 * 32];
    const int t = threadIdx.x, w = t >> 6, lane = t & 63;
    const int ln15 = lane & 15, quad = lane >> 4;
    const int wr = w >> 1, wc = w & 1;
    const int n0 = blockIdx.x * 128, m0 = blockIdx.y * 128;
    const int srow = lane >> 2;
    const int sg = (lane & 3) * 8;

    f32x4 acc[4][4] = {};
    for (int k0 = 0; k0 < D_; k0 += 32) {
#pragma unroll
        for (int c = 0; c < 2; ++c) {
            const int cc = w * 2 + c;
            const int row = cc * 16 + srow;
            gl_lds16(A + (size_t)(m0 + row) * D_ + k0 + sg, As + cc * 512);
            gl_lds16(Wm + (size_t)(n0 + row) * D_ + k0 + sg, Bs + cc * 512);
        }
        __syncthreads();
        short8 af[4], bf[4];
#pragma unroll
        for (int i = 0; i < 4; ++i) {
            af[i] = *(const short8*)(As + (wr * 64 + i * 16 + ln15) * 32 + quad * 8);
            bf[i] = *(const short8*)(Bs + (wc * 64 + i * 16 + ln15) * 32 + quad * 8);
        }
#pragma unroll
        for (int mt = 0; mt < 4; ++mt)
#pragma unroll
            for (int nt = 0; nt < 4; ++nt)
                acc[mt][nt] = __builtin_amdgcn_mfma_f32_16x16x32_bf16(
                    af[mt], bf[nt], acc[mt][nt], 0, 0, 0);
        __syncthreads();
    }
#pragma unroll
    for (int mt = 0; mt < 4; ++mt) {
#pragma unroll
        for (int r = 0; r < 4; ++r) {
            const int row = m0 + wr * 64 + mt * 16 + quad * 4 + r;
#pragma unroll
            for (int nt = 0; nt < 4; ++nt) {
                const int col = n0 + wc * 64 + nt * 16 + ln15;
                out[(size_t)row * D_ + col] = acc[mt][nt][r] + bias[col];
            }
        }
    }
}

// ---------------------------------------------------------------------------
// Flash attention, no-LDS P path, fully mt-outer: QK^T(mt) -> P(mt) ->
// PV-partial(mt). ap/pk/sc all transient within one mt iteration; peak live
// regs ~110 -> target <=128 total (4 blocks/CU, grid exactly co-resident).
// Cost: bv4 reloaded per mt (+8 ds_read_b128/tile, LGKM pipe, conflict-free).
// ---------------------------------------------------------------------------
__global__ __launch_bounds__(256, 4) void attn_mfma(
    const ushort* __restrict__ Qd, const ushort* __restrict__ Kd,
    const ushort* __restrict__ Vtg, const ushort* __restrict__ mpk,
    ushort* __restrict__ ctx) {
    __shared__ ushort Ks[2][64 * 64];  // [key][dk], swizzled groups
    __shared__ ushort Vt[2][64 * 64];  // [dk][key], swizzled groups

    const int t = threadIdx.x, w = t >> 6, lane = t & 63;
    const int ln15 = lane & 15, quad = lane >> 4;
    const int lp = lane & 7, lr8 = lane >> 3;
    const int bh = blockIdx.y, b = bh >> 4, h = bh & 15;
    const int q0 = blockIdx.x * 128;

    const ushort* Qb = Qd + (size_t)bh * (S_ * DK_);
    const ushort* Kb = Kd + (size_t)bh * (S_ * DK_);
    const ushort* Vb = Vtg + (size_t)bh * (DK_ * S_);  // [dk][s] swizzled
    // packed mask: ushort at ((b*32 + kt)*2048 + qrow)*4 + quad
    const ushort* mb = mpk + (size_t)b * 32 * 2048 * 4;

    int mof[2];
#pragma unroll
    for (int mt = 0; mt < 2; ++mt)
        mof[mt] = ((q0 + w * 32 + mt * 16 + ln15) << 2) + quad;

    // Q fragments: loaded once, live in registers all kernel (B-operand)
    short8 aq[2][2];  // [ks][mt]
#pragma unroll
    for (int ks = 0; ks < 2; ++ks)
#pragma unroll
        for (int mt = 0; mt < 2; ++mt)
            aq[ks][mt] = *(const short8*)(
                Qb + (size_t)(q0 + w * 32 + mt * 16 + ln15) * DK_ + ks * 32 + quad * 8);

    // stage K/V tile kt into buffer p (async; drained by the NEXT barrier)
    auto stageKV = [&](int kt, int p) {
        const int k0 = kt * 64;
#pragma unroll
        for (int c = 0; c < 2; ++c) {
            const int cc = w * 2 + c;
            const int row = cc * 8 + lr8;  // K: key row; V: dk row
            gl_lds16(Kb + (size_t)(k0 + row) * DK_ + (lp ^ lr8) * 8, &Ks[p][cc * 512]);
            gl_lds16(Vb + (size_t)row * S_ + k0 + lp * 8, &Vt[p][cc * 512]);
        }
    };

    stageKV(0, 0);
    unsigned mv[2];
    mv[0] = mb[mof[0]];
    mv[1] = mb[mof[1]];

    f32x4 O[2][4] = {};
    f32x4 lsum[2] = {};
    short8 vone;
#pragma unroll
    for (int j = 0; j < 8; ++j) vone[j] = (short)0x3F80;  // bf16(1.0)

    int p = 0;
    for (int kt = 0; kt < S_ / 64; ++kt) {
        __syncthreads();  // drains stageKV(kt); buffer p^1 now free
        if (kt < S_ / 64 - 1) stageKV(kt + 1, p ^ 1);

#pragma unroll
        for (int mt = 0; mt < 2; ++mt) {
            // ---- S'^T = K (Q*QSCALE)^T for this mt
            f32x4 sc[4] = {};
            __builtin_amdgcn_s_setprio(1);
#pragma unroll
            for (int ks = 0; ks < 2; ++ks) {
#pragma unroll
                for (int nt = 0; nt < 4; ++nt) {
                    const int row = nt * 16 + ln15;
                    const short8 bk = *(const short8*)(
                        &Ks[p][row * 64 + ((ks * 4 + quad) ^ (row & 7)) * 8]);
                    sc[nt] = __builtin_amdgcn_mfma_f32_16x16x32_bf16(
                        bk, aq[ks][mt], sc[nt], 0, 0, 0);
                }
            }
            __builtin_amdgcn_s_setprio(0);

            // ---- P = maskbit ? exp2 : 0, pack bf16, permlane32 -> A-frags
            unsigned pk[4][2];
#pragma unroll
            for (int nt = 0; nt < 4; ++nt) {
                float pv[4];
#pragma unroll
                for (int r = 0; r < 4; ++r) {
                    const float e = __builtin_amdgcn_exp2f(sc[nt][r]);
                    // bit nt*4+r of mv -> 0 / 0xFFFFFFFF, AND with float bits
                    const unsigned msk =
                        (unsigned)((int)(mv[mt] << (31 - (nt * 4 + r))) >> 31);
                    pv[r] = __uint_as_float(__float_as_uint(e) & msk);
                }
                pk[nt][0] = cvt_pk_bf16(pv[0], pv[1]);
                pk[nt][1] = cvt_pk_bf16(pv[2], pv[3]);
            }
            pl32_swap(pk[0][0], pk[1][0]);
            pl32_swap(pk[0][1], pk[1][1]);
            pl32_swap(pk[2][0], pk[3][0]);
            pl32_swap(pk[2][1], pk[3][1]);
            const short8 ap0 = mk8(pk[0][0], pk[1][0], pk[0][1], pk[1][1]);
            const short8 ap1 = mk8(pk[2][0], pk[3][0], pk[2][1], pk[3][1]);

            // ---- O[mt] += P V^T ; lsum[mt] += P @ ones
#pragma unroll
            for (int ks = 0; ks < 2; ++ks) {
                const short8 apx = ks ? ap1 : ap0;
                short8 bv4[4];
#pragma unroll
                for (int nt = 0; nt < 4; ++nt) {
                    const int dim = nt * 16 + ln15;
                    bv4[nt] = *(const short8*)(
                        &Vt[p][dim * 64 + ((ks * 4 + quad) ^ (dim & 7)) * 8]);
                }
                __builtin_amdgcn_s_setprio(1);
#pragma unroll
                for (int nt = 0; nt < 4; ++nt)
                    O[mt][nt] = __builtin_amdgcn_mfma_f32_16x16x32_bf16(
                        apx, bv4[nt], O[mt][nt], 0, 0, 0);
                lsum[mt] = __builtin_amdgcn_mfma_f32_16x16x32_bf16(
                    apx, vone, lsum[mt], 0, 0, 0);
                __builtin_amdgcn_s_setprio(0);
            }
        }

        // prefetch mask for kt+1 (both mv dead here)
        if (kt < S_ / 64 - 1) {
            mv[0] = mb[(kt + 1) * 8192 + mof[0]];
            mv[1] = mb[(kt + 1) * 8192 + mof[1]];
        }
        p ^= 1;
    }

    // finalize: ctx[b][s][h*64+dim] = O / lsum (bf16, feeds out-proj)
#pragma unroll
    for (int mt = 0; mt < 2; ++mt) {
#pragma unroll
        for (int r = 0; r < 4; ++r) {
            const int qg = q0 + w * 32 + mt * 16 + quad * 4 + r;
            const float inv = __builtin_amdgcn_rcpf(lsum[mt][r]);
#pragma unroll
            for (int nt = 0; nt < 4; ++nt) {
                const int dim = nt * 16 + ln15;
                ctx[((size_t)b * S_ + qg) * D_ + h * DK_ + dim] = f2bf(O[mt][nt][r] * inv);
            }
        }
    }
}

// ---------------------------------------------------------------------------
extern "C" void kernel_launch(void* const* d_in, const int* in_sizes, int n_in,
                              void* d_out, int out_size, void* d_ws, size_t ws_size,
                              hipStream_t stream) {
    (void)in_sizes; (void)n_in; (void)out_size; (void)ws_size;
    const float* query = (const float*)d_in[0];
    const float* key_  = (const float*)d_in[1];
    const float* value = (const float*)d_in[2];
    const int*   mask  = (const int*)d_in[3];
    const float* Wq = (const float*)d_in[4];
    const float* bq = (const float*)d_in[5];
    const float* Wk = (const float*)d_in[6];
    const float* bk = (const float*)d_in[7];
    const float* Wv = (const float*)d_in[8];
    const float* bv = (const float*)d_in[9];
    const float* Wo = (const float*)d_in[10];
    const float* bo = (const float*)d_in[11];
    float* out = (float*)d_out;

    const size_t nX = (size_t)B_ * S_ * D_;  // 8,388,608
    const size_t nW = (size_t)D_ * D_;       // 1,048,576
    ushort* qkv = (ushort*)d_ws;       // 3*nX bf16 (q,k,v casts)
    ushort* Wb  = qkv + 3 * nX;        // 4*nW bf16
    ushort* Qd  = Wb + 4 * nW;
    ushort* Kd  = Qd + nX;
    ushort* Vt  = Kd + nX;             // V^T [bh][dk][s], kappa+XOR permuted
    unsigned long long* mpk = (unsigned long long*)(Vt + nX);  // 2 MB
    ushort* ctx = qkv;                 // q-cast region, dead after gemm_proj

    // 14336 cast blocks + 65536 mask blocks (B*S*S/256)
    cast_mask<<<79872, 256, 0, stream>>>(query, key_, value, Wq, Wk, Wv, Wo,
                                         mask, qkv, Wb, mpk);

    dim3 gp(D_ / 128, (B_ * S_) / 128, 3);  // (8, 64, 3)
    gemm_proj<<<gp, 256, 0, stream>>>(qkv, qkv + nX, qkv + 2 * nX, Wb,
                                      bq, bk, bv, Qd, Kd, Vt);

    dim3 ga(S_ / 128, B_ * H_);  // (16, 64)
    attn_mfma<<<ga, 256, 0, stream>>>(Qd, Kd, Vt, (const ushort*)mpk, ctx);

    dim3 go(D_ / 128, (B_ * S_) / 128);  // (8, 64)
    gemm_out<<<go, 256, 0, stream>>>(ctx, Wb + 3 * nW, bo, out);
}

// Round 6
// 416.232 us; speedup vs baseline: 1.4315x; 1.0209x over previous
//
#include <hip/hip_runtime.h>

#define B_  4
#define S_  2048
#define D_  1024
#define H_  16
#define DK_ 64

typedef unsigned short ushort;
typedef __attribute__((ext_vector_type(8))) short short8;
typedef __attribute__((ext_vector_type(8))) unsigned short ushort8;
typedef __attribute__((ext_vector_type(4))) float f32x4;

// scores use exp2: fold 0.125 * log2(e) into Q at projection time
#define QSCALE 0.18033688011112042f

__device__ __forceinline__ ushort f2bf(float f) {  // RNE
    unsigned int u = __float_as_uint(f);
    u += 0x7fffu + ((u >> 16) & 1u);
    return (ushort)(u >> 16);
}

__device__ __forceinline__ unsigned cvt_pk_bf16(float lo, float hi) {
    unsigned r;
    asm("v_cvt_pk_bf16_f32 %0, %1, %2" : "=v"(r) : "v"(lo), "v"(hi));
    return r;
}
// swaps a[32:63] <-> b[0:31]
__device__ __forceinline__ void pl32_swap(unsigned& a, unsigned& b) {
    asm("v_permlane32_swap_b32 %0, %1" : "+v"(a), "+v"(b));
}
__device__ __forceinline__ short8 mk8(unsigned a, unsigned b, unsigned c,
                                      unsigned d) {
    union { unsigned u[4]; short8 s; } x;
    x.u[0] = a; x.u[1] = b; x.u[2] = c; x.u[3] = d;
    return x.s;
}

__device__ __forceinline__ void gl_lds16(const ushort* g, ushort* ldsbase) {
    __builtin_amdgcn_global_load_lds(
        (const __attribute__((address_space(1))) void*)g,
        (__attribute__((address_space(3))) void*)ldsbase, 16, 0, 0);
}

// ---------------------------------------------------------------------------
// Merged: cast q,k,v + Wq,Wk,Wv,Wo to bf16 (blocks 0..14335) AND mask pack
// (blocks 14336..79871 — 65536 mask blocks, B*S*S/256). Mask pack: per
// 64-key window, lane L reads key kappa(L) so __ballot directly yields the
// quad-chunked word: bit (quad*16 + nt*4 + r) = mask at key
// (nt*16 + quad*4 + r). Layout mpk[b][kt][q] (ull) -> attn reads ONE
// ushort: [b][kt][q][quad].
// ---------------------------------------------------------------------------
__global__ __launch_bounds__(256) void cast_mask(
    const float* __restrict__ q, const float* __restrict__ k,
    const float* __restrict__ v, const float* __restrict__ Wq,
    const float* __restrict__ Wk, const float* __restrict__ Wv,
    const float* __restrict__ Wo, const int* __restrict__ m,
    ushort* __restrict__ qkv_dst, ushort* __restrict__ w_dst,
    unsigned long long* __restrict__ mpk) {
    int bid = blockIdx.x;
    if (bid >= 14336) {  // ---- mask pack path (65536 blocks)
        bid -= 14336;
        const size_t idx = (size_t)bid * 256 + threadIdx.x;
        const int lane = threadIdx.x & 63;
        const size_t wbase = idx & ~(size_t)63;
        const int kap = (((lane >> 2) & 3) << 4) | ((lane >> 4) << 2) | (lane & 3);
        const unsigned long long W = __ballot(m[wbase + kap] != 0);
        if (lane == 0) {
            const size_t widx = wbase >> 6;
            const int kt = (int)(widx & 31);
            const int qq = (int)((widx >> 5) & 2047);
            const int bb = (int)(widx >> 16);
            mpk[((size_t)bb * 32 + kt) * 2048 + qq] = W;
        }
        return;
    }
    const float* src;
    ushort* dst;
    int lb;
    if (bid < 12288) {
        const int s = bid >> 12;
        lb = bid & 4095;
        src = (s == 0) ? q : (s == 1) ? k : v;
        dst = qkv_dst + (size_t)s * (B_ * S_ * D_);
    } else {
        const int wi = (bid - 12288) >> 9;
        lb = (bid - 12288) & 511;
        src = (wi == 0) ? Wq : (wi == 1) ? Wk : (wi == 2) ? Wv : Wo;
        dst = w_dst + (size_t)wi * (D_ * D_);
    }
    const int i = lb * 2048 + threadIdx.x * 8;
    const float4 a = *(const float4*)(src + i);
    const float4 b = *(const float4*)(src + i + 4);
    ushort8 r;
    r[0] = f2bf(a.x); r[1] = f2bf(a.y); r[2] = f2bf(a.z); r[3] = f2bf(a.w);
    r[4] = f2bf(b.x); r[5] = f2bf(b.y); r[6] = f2bf(b.z); r[7] = f2bf(b.w);
    *(ushort8*)(dst + i) = r;
}

// ---------------------------------------------------------------------------
// Fused Q/K/V projection (blockIdx.z selects). out = (A @ W^T + b)*scale.
// z=0/1: bf16 scatter to [B,H,S,DK]. z=2: writes V^T [bh][dk][s] directly
// with the kappa+XOR key permutation folded in.
// XCD-chunked block swizzle: each XCD gets 8 contiguous A-panels (2 MB) x
// all 8 W-panels (2 MB) -> working set == private L2. LDS chunk XOR-swizzle
// (both sides: pre-swizzled gl_lds source + swizzled ds_read) cuts the 64B
// row-stride bank conflict from 8-way to 4-way.
// ---------------------------------------------------------------------------
__global__ __launch_bounds__(256) void gemm_proj(
    const ushort* __restrict__ qb, const ushort* __restrict__ kb,
    const ushort* __restrict__ vb, const ushort* __restrict__ Wb,
    const float* __restrict__ bq, const float* __restrict__ bk,
    const float* __restrict__ bv, ushort* __restrict__ Qd,
    ushort* __restrict__ Kd, ushort* __restrict__ Vt) {
    const int z = blockIdx.z;
    const ushort* A  = (z == 0) ? qb : (z == 1) ? kb : vb;
    const ushort* Wm = Wb + (size_t)z * (D_ * D_);
    const float* bias = (z == 0) ? bq : (z == 1) ? bk : bv;
    const float scale = (z == 0) ? QSCALE : 1.0f;

    __shared__ ushort As[128 * 32];
    __shared__ ushort Bs[128 * 32];
    const int t = threadIdx.x, w = t >> 6, lane = t & 63;
    const int ln15 = lane & 15, quad = lane >> 4;
    const int wr = w >> 1, wc = w & 1;
    // XCD-chunked swizzle: lin%8 == dispatch XCD; give it y in [8k,8k+8)
    const int lin = blockIdx.y * 8 + blockIdx.x;  // 0..511
    const int jj_ = lin >> 3;                     // 0..63
    const int ny = (lin & 7) * 8 + (jj_ & 7);     // A-panel row block
    const int nx = jj_ >> 3;                      // W-panel col block
    const int n0 = nx * 128, m0 = ny * 128;
    const int srow = lane >> 2;
    // pre-swizzled source chunk: physical chunk (lane&3) holds logical
    // chunk (lane&3)^(srow&3)
    const int sgs = ((lane & 3) ^ (srow & 3)) * 8;
    const int cx = ln15 & 3;  // read-side XOR key (row&3)

    f32x4 acc[4][4] = {};
    for (int k0 = 0; k0 < D_; k0 += 32) {
#pragma unroll
        for (int c = 0; c < 2; ++c) {
            const int cc = w * 2 + c;
            const int row = cc * 16 + srow;
            gl_lds16(A + (size_t)(m0 + row) * D_ + k0 + sgs, As + cc * 512);
            gl_lds16(Wm + (size_t)(n0 + row) * D_ + k0 + sgs, Bs + cc * 512);
        }
        __syncthreads();
        short8 af[4], bf[4];
#pragma unroll
        for (int i = 0; i < 4; ++i) {
            af[i] = *(const short8*)(As + (wr * 64 + i * 16 + ln15) * 32 + (quad ^ cx) * 8);
            bf[i] = *(const short8*)(Bs + (wc * 64 + i * 16 + ln15) * 32 + (quad ^ cx) * 8);
        }
#pragma unroll
        for (int mt = 0; mt < 4; ++mt)
#pragma unroll
            for (int nt = 0; nt < 4; ++nt)
                acc[mt][nt] = __builtin_amdgcn_mfma_f32_16x16x32_bf16(
                    af[mt], bf[nt], acc[mt][nt], 0, 0, 0);
        __syncthreads();
    }
#pragma unroll
    for (int mt = 0; mt < 4; ++mt) {
#pragma unroll
        for (int r = 0; r < 4; ++r) {
            const int row = m0 + wr * 64 + mt * 16 + quad * 4 + r;
            const int bb = row >> 11, s = row & (S_ - 1);
            if (z == 2) {
                // inverse kappa: token-in-window m -> sg*8+j
                const int mm = s & 63, s0w = s & ~63;
                const int g2 = ((mm >> 2) & 1) | ((mm >> 3) & 2);
                const int sgi = ((mm >> 5) & 1) * 4 + g2;
                const int jj = (mm & 1) | ((mm >> 2) & 2) | ((mm << 1) & 4);
#pragma unroll
                for (int nt = 0; nt < 4; ++nt) {
                    const int col = n0 + wc * 64 + nt * 16 + ln15;
                    const float vv = acc[mt][nt][r] + bias[col];
                    const int h = col >> 6, dk = col & 63;
                    const int phys = ((sgi ^ (dk & 7)) << 3) | jj;
                    Vt[((((size_t)bb * H_ + h) * DK_ + dk) << 11) + s0w + phys] =
                        f2bf(vv);
                }
            } else {
#pragma unroll
                for (int nt = 0; nt < 4; ++nt) {
                    const int col = n0 + wc * 64 + nt * 16 + ln15;
                    const float vv = (acc[mt][nt][r] + bias[col]) * scale;
                    const int h = col >> 6, dk = col & 63;
                    ushort* outp = (z == 0) ? Qd : Kd;
                    outp[((((size_t)bb * H_ + h) * S_ + s) << 6) + dk] = f2bf(vv);
                }
            }
        }
    }
}

// ---------------------------------------------------------------------------
// Output projection: fp32 out = A @ W^T + b, flat [M,D]. Same XCD swizzle +
// LDS chunk XOR as gemm_proj.
// ---------------------------------------------------------------------------
__global__ __launch_bounds__(256) void gemm_out(const ushort* __restrict__ A,
                                                const ushort* __restrict__ Wm,
                                                const float* __restrict__ bias,
                                                float* __restrict__ out) {
    __shared__ ushort As[128 * 32];
    __shared__ ushort Bs[128 * 32];
    const int t = threadIdx.x, w = t >> 6, lane = t & 63;
    const int ln15 = lane & 15, quad = lane >> 4;
    const int wr = w >> 1, wc = w & 1;
    const int lin = blockIdx.y * 8 + blockIdx.x;  // 0..511
    const int jj_ = lin >> 3;
    const int ny = (lin & 7) * 8 + (jj_ & 7);
    const int nx = jj_ >> 3;
    const int n0 = nx * 128, m0 = ny * 128;
    const int srow = lane >> 2;
    const int sgs = ((lane & 3) ^ (srow & 3)) * 8;
    const int cx = ln15 & 3;

    f32x4 acc[4][4] = {};
    for (int k0 = 0; k0 < D_; k0 += 32) {
#pragma unroll
        for (int c = 0; c < 2; ++c) {
            const int cc = w * 2 + c;
            const int row = cc * 16 + srow;
            gl_lds16(A + (size_t)(m0 + row) * D_ + k0 + sgs, As + cc * 512);
            gl_lds16(Wm + (size_t)(n0 + row) * D_ + k0 + sgs, Bs + cc * 512);
        }
        __syncthreads();
        short8 af[4], bf[4];
#pragma unroll
        for (int i = 0; i < 4; ++i) {
            af[i] = *(const short8*)(As + (wr * 64 + i * 16 + ln15) * 32 + (quad ^ cx) * 8);
            bf[i] = *(const short8*)(Bs + (wc * 64 + i * 16 + ln15) * 32 + (quad ^ cx) * 8);
        }
#pragma unroll
        for (int mt = 0; mt < 4; ++mt)
#pragma unroll
            for (int nt = 0; nt < 4; ++nt)
                acc[mt][nt] = __builtin_amdgcn_mfma_f32_16x16x32_bf16(
                    af[mt], bf[nt], acc[mt][nt], 0, 0, 0);
        __syncthreads();
    }
#pragma unroll
    for (int mt = 0; mt < 4; ++mt) {
#pragma unroll
        for (int r = 0; r < 4; ++r) {
            const int row = m0 + wr * 64 + mt * 16 + quad * 4 + r;
#pragma unroll
            for (int nt = 0; nt < 4; ++nt) {
                const int col = n0 + wc * 64 + nt * 16 + ln15;
                out[(size_t)row * D_ + col] = acc[mt][nt][r] + bias[col];
            }
        }
    }
}

// ---------------------------------------------------------------------------
// Flash attention, no-LDS P path, fully mt-outer (round-5 verified).
// XCD-chunked swizzle: each XCD owns 8 bh (K+V = 4 MB, exactly L2).
// ---------------------------------------------------------------------------
__global__ __launch_bounds__(256, 4) void attn_mfma(
    const ushort* __restrict__ Qd, const ushort* __restrict__ Kd,
    const ushort* __restrict__ Vtg, const ushort* __restrict__ mpk,
    ushort* __restrict__ ctx) {
    __shared__ ushort Ks[2][64 * 64];  // [key][dk], swizzled groups
    __shared__ ushort Vt[2][64 * 64];  // [dk][key], swizzled groups

    const int t = threadIdx.x, w = t >> 6, lane = t & 63;
    const int ln15 = lane & 15, quad = lane >> 4;
    const int lp = lane & 7, lr8 = lane >> 3;
    // XCD-chunked: lin%8 == dispatch XCD -> bh in [8k, 8k+8), all 16 q-blocks
    const int lin = blockIdx.y * 16 + blockIdx.x;  // 0..1023
    const int jq = lin >> 3;                       // 0..127
    const int bh = (lin & 7) * 8 + (jq & 7);
    const int q0 = (jq >> 3) * 128;
    const int b = bh >> 4, h = bh & 15;

    const ushort* Qb = Qd + (size_t)bh * (S_ * DK_);
    const ushort* Kb = Kd + (size_t)bh * (S_ * DK_);
    const ushort* Vb = Vtg + (size_t)bh * (DK_ * S_);  // [dk][s] swizzled
    // packed mask: ushort at ((b*32 + kt)*2048 + qrow)*4 + quad
    const ushort* mb = mpk + (size_t)b * 32 * 2048 * 4;

    int mof[2];
#pragma unroll
    for (int mt = 0; mt < 2; ++mt)
        mof[mt] = ((q0 + w * 32 + mt * 16 + ln15) << 2) + quad;

    // Q fragments: loaded once, live in registers all kernel (B-operand)
    short8 aq[2][2];  // [ks][mt]
#pragma unroll
    for (int ks = 0; ks < 2; ++ks)
#pragma unroll
        for (int mt = 0; mt < 2; ++mt)
            aq[ks][mt] = *(const short8*)(
                Qb + (size_t)(q0 + w * 32 + mt * 16 + ln15) * DK_ + ks * 32 + quad * 8);

    // stage K/V tile kt into buffer p (async; drained by the NEXT barrier)
    auto stageKV = [&](int kt, int p) {
        const int k0 = kt * 64;
#pragma unroll
        for (int c = 0; c < 2; ++c) {
            const int cc = w * 2 + c;
            const int row = cc * 8 + lr8;  // K: key row; V: dk row
            gl_lds16(Kb + (size_t)(k0 + row) * DK_ + (lp ^ lr8) * 8, &Ks[p][cc * 512]);
            gl_lds16(Vb + (size_t)row * S_ + k0 + lp * 8, &Vt[p][cc * 512]);
        }
    };

    stageKV(0, 0);
    unsigned mv[2];
    mv[0] = mb[mof[0]];
    mv[1] = mb[mof[1]];

    f32x4 O[2][4] = {};
    f32x4 lsum[2] = {};
    short8 vone;
#pragma unroll
    for (int j = 0; j < 8; ++j) vone[j] = (short)0x3F80;  // bf16(1.0)

    int p = 0;
    for (int kt = 0; kt < S_ / 64; ++kt) {
        __syncthreads();  // drains stageKV(kt); buffer p^1 now free
        if (kt < S_ / 64 - 1) stageKV(kt + 1, p ^ 1);

#pragma unroll
        for (int mt = 0; mt < 2; ++mt) {
            // ---- S'^T = K (Q*QSCALE)^T for this mt
            f32x4 sc[4] = {};
            __builtin_amdgcn_s_setprio(1);
#pragma unroll
            for (int ks = 0; ks < 2; ++ks) {
#pragma unroll
                for (int nt = 0; nt < 4; ++nt) {
                    const int row = nt * 16 + ln15;
                    const short8 bk = *(const short8*)(
                        &Ks[p][row * 64 + ((ks * 4 + quad) ^ (row & 7)) * 8]);
                    sc[nt] = __builtin_amdgcn_mfma_f32_16x16x32_bf16(
                        bk, aq[ks][mt], sc[nt], 0, 0, 0);
                }
            }
            __builtin_amdgcn_s_setprio(0);

            // ---- P = maskbit ? exp2 : 0, pack bf16, permlane32 -> A-frags
            unsigned pk[4][2];
#pragma unroll
            for (int nt = 0; nt < 4; ++nt) {
                float pv[4];
#pragma unroll
                for (int r = 0; r < 4; ++r) {
                    const float e = __builtin_amdgcn_exp2f(sc[nt][r]);
                    // bit nt*4+r of mv -> 0 / 0xFFFFFFFF, AND with float bits
                    const unsigned msk =
                        (unsigned)((int)(mv[mt] << (31 - (nt * 4 + r))) >> 31);
                    pv[r] = __uint_as_float(__float_as_uint(e) & msk);
                }
                pk[nt][0] = cvt_pk_bf16(pv[0], pv[1]);
                pk[nt][1] = cvt_pk_bf16(pv[2], pv[3]);
            }
            pl32_swap(pk[0][0], pk[1][0]);
            pl32_swap(pk[0][1], pk[1][1]);
            pl32_swap(pk[2][0], pk[3][0]);
            pl32_swap(pk[2][1], pk[3][1]);
            const short8 ap0 = mk8(pk[0][0], pk[1][0], pk[0][1], pk[1][1]);
            const short8 ap1 = mk8(pk[2][0], pk[3][0], pk[2][1], pk[3][1]);

            // ---- O[mt] += P V^T ; lsum[mt] += P @ ones
#pragma unroll
            for (int ks = 0; ks < 2; ++ks) {
                const short8 apx = ks ? ap1 : ap0;
                short8 bv4[4];
#pragma unroll
                for (int nt = 0; nt < 4; ++nt) {
                    const int dim = nt * 16 + ln15;
                    bv4[nt] = *(const short8*)(
                        &Vt[p][dim * 64 + ((ks * 4 + quad) ^ (dim & 7)) * 8]);
                }
                __builtin_amdgcn_s_setprio(1);
#pragma unroll
                for (int nt = 0; nt < 4; ++nt)
                    O[mt][nt] = __builtin_amdgcn_mfma_f32_16x16x32_bf16(
                        apx, bv4[nt], O[mt][nt], 0, 0, 0);
                lsum[mt] = __builtin_amdgcn_mfma_f32_16x16x32_bf16(
                    apx, vone, lsum[mt], 0, 0, 0);
                __builtin_amdgcn_s_setprio(0);
            }
        }

        // prefetch mask for kt+1 (both mv dead here)
        if (kt < S_ / 64 - 1) {
            mv[0] = mb[(kt + 1) * 8192 + mof[0]];
            mv[1] = mb[(kt + 1) * 8192 + mof[1]];
        }
        p ^= 1;
    }

    // finalize: ctx[b][s][h*64+dim] = O / lsum (bf16, feeds out-proj)
#pragma unroll
    for (int mt = 0; mt < 2; ++mt) {
#pragma unroll
        for (int r = 0; r < 4; ++r) {
            const int qg = q0 + w * 32 + mt * 16 + quad * 4 + r;
            const float inv = __builtin_amdgcn_rcpf(lsum[mt][r]);
#pragma unroll
            for (int nt = 0; nt < 4; ++nt) {
                const int dim = nt * 16 + ln15;
                ctx[((size_t)b * S_ + qg) * D_ + h * DK_ + dim] = f2bf(O[mt][nt][r] * inv);
            }
        }
    }
}

// ---------------------------------------------------------------------------
extern "C" void kernel_launch(void* const* d_in, const int* in_sizes, int n_in,
                              void* d_out, int out_size, void* d_ws, size_t ws_size,
                              hipStream_t stream) {
    (void)in_sizes; (void)n_in; (void)out_size; (void)ws_size;
    const float* query = (const float*)d_in[0];
    const float* key_  = (const float*)d_in[1];
    const float* value = (const float*)d_in[2];
    const int*   mask  = (const int*)d_in[3];
    const float* Wq = (const float*)d_in[4];
    const float* bq = (const float*)d_in[5];
    const float* Wk = (const float*)d_in[6];
    const float* bk = (const float*)d_in[7];
    const float* Wv = (const float*)d_in[8];
    const float* bv = (const float*)d_in[9];
    const float* Wo = (const float*)d_in[10];
    const float* bo = (const float*)d_in[11];
    float* out = (float*)d_out;

    const size_t nX = (size_t)B_ * S_ * D_;  // 8,388,608
    const size_t nW = (size_t)D_ * D_;       // 1,048,576
    ushort* qkv = (ushort*)d_ws;       // 3*nX bf16 (q,k,v casts)
    ushort* Wb  = qkv + 3 * nX;        // 4*nW bf16
    ushort* Qd  = Wb + 4 * nW;
    ushort* Kd  = Qd + nX;
    ushort* Vt  = Kd + nX;             // V^T [bh][dk][s], kappa+XOR permuted
    unsigned long long* mpk = (unsigned long long*)(Vt + nX);  // 2 MB
    ushort* ctx = qkv;                 // q-cast region, dead after gemm_proj

    // 14336 cast blocks + 65536 mask blocks (B*S*S/256)
    cast_mask<<<79872, 256, 0, stream>>>(query, key_, value, Wq, Wk, Wv, Wo,
                                         mask, qkv, Wb, mpk);

    dim3 gp(D_ / 128, (B_ * S_) / 128, 3);  // (8, 64, 3)
    gemm_proj<<<gp, 256, 0, stream>>>(qkv, qkv + nX, qkv + 2 * nX, Wb,
                                      bq, bk, bv, Qd, Kd, Vt);

    dim3 ga(S_ / 128, B_ * H_);  // (16, 64)
    attn_mfma<<<ga, 256, 0, stream>>>(Qd, Kd, Vt, (const ushort*)mpk, ctx);

    dim3 go(D_ / 128, (B_ * S_) / 128);  // (8, 64)
    gemm_out<<<go, 256, 0, stream>>>(ctx, Wb + 3 * nW, bo, out);
}

// Round 7
// 416.070 us; speedup vs baseline: 1.4321x; 1.0004x over previous
//
#include <hip/hip_runtime.h>

#define B_  4
#define S_  2048
#define D_  1024
#define H_  16
#define DK_ 64

typedef unsigned short ushort;
typedef __attribute__((ext_vector_type(8))) short short8;
typedef __attribute__((ext_vector_type(8))) unsigned short ushort8;
typedef __attribute__((ext_vector_type(4))) float f32x4;

// scores use exp2: fold 0.125 * log2(e) into Q at projection time
#define QSCALE 0.18033688011112042f

__device__ __forceinline__ ushort f2bf(float f) {  // RNE
    unsigned int u = __float_as_uint(f);
    u += 0x7fffu + ((u >> 16) & 1u);
    return (ushort)(u >> 16);
}

__device__ __forceinline__ unsigned cvt_pk_bf16(float lo, float hi) {
    unsigned r;
    asm("v_cvt_pk_bf16_f32 %0, %1, %2" : "=v"(r) : "v"(lo), "v"(hi));
    return r;
}
// swaps a[32:63] <-> b[0:31]
__device__ __forceinline__ void pl32_swap(unsigned& a, unsigned& b) {
    asm("v_permlane32_swap_b32 %0, %1" : "+v"(a), "+v"(b));
}
__device__ __forceinline__ short8 mk8(unsigned a, unsigned b, unsigned c,
                                      unsigned d) {
    union { unsigned u[4]; short8 s; } x;
    x.u[0] = a; x.u[1] = b; x.u[2] = c; x.u[3] = d;
    return x.s;
}

__device__ __forceinline__ void gl_lds16(const ushort* g, ushort* ldsbase) {
    __builtin_amdgcn_global_load_lds(
        (const __attribute__((address_space(1))) void*)g,
        (__attribute__((address_space(3))) void*)ldsbase, 16, 0, 0);
}

// ---------------------------------------------------------------------------
// Merged: cast q,k,v + Wq,Wk,Wv,Wo to bf16 (blocks 0..14335) AND mask pack
// (blocks 14336..79871 — 65536 mask blocks, B*S*S/256). Mask pack: per
// 64-key window, lane L reads key kappa(L) so __ballot directly yields the
// quad-chunked word: bit (quad*16 + nt*4 + r) = mask at key
// (nt*16 + quad*4 + r). Layout mpk[b][kt][q] (ull) -> attn reads ONE
// ushort: [b][kt][q][quad].
// ---------------------------------------------------------------------------
__global__ __launch_bounds__(256) void cast_mask(
    const float* __restrict__ q, const float* __restrict__ k,
    const float* __restrict__ v, const float* __restrict__ Wq,
    const float* __restrict__ Wk, const float* __restrict__ Wv,
    const float* __restrict__ Wo, const int* __restrict__ m,
    ushort* __restrict__ qkv_dst, ushort* __restrict__ w_dst,
    unsigned long long* __restrict__ mpk) {
    int bid = blockIdx.x;
    if (bid >= 14336) {  // ---- mask pack path (65536 blocks)
        bid -= 14336;
        const size_t idx = (size_t)bid * 256 + threadIdx.x;
        const int lane = threadIdx.x & 63;
        const size_t wbase = idx & ~(size_t)63;
        const int kap = (((lane >> 2) & 3) << 4) | ((lane >> 4) << 2) | (lane & 3);
        const unsigned long long W = __ballot(m[wbase + kap] != 0);
        if (lane == 0) {
            const size_t widx = wbase >> 6;
            const int kt = (int)(widx & 31);
            const int qq = (int)((widx >> 5) & 2047);
            const int bb = (int)(widx >> 16);
            mpk[((size_t)bb * 32 + kt) * 2048 + qq] = W;
        }
        return;
    }
    const float* src;
    ushort* dst;
    int lb;
    if (bid < 12288) {
        const int s = bid >> 12;
        lb = bid & 4095;
        src = (s == 0) ? q : (s == 1) ? k : v;
        dst = qkv_dst + (size_t)s * (B_ * S_ * D_);
    } else {
        const int wi = (bid - 12288) >> 9;
        lb = (bid - 12288) & 511;
        src = (wi == 0) ? Wq : (wi == 1) ? Wk : (wi == 2) ? Wv : Wo;
        dst = w_dst + (size_t)wi * (D_ * D_);
    }
    const int i = lb * 2048 + threadIdx.x * 8;
    const float4 a = *(const float4*)(src + i);
    const float4 b = *(const float4*)(src + i + 4);
    ushort8 r;
    r[0] = f2bf(a.x); r[1] = f2bf(a.y); r[2] = f2bf(a.z); r[3] = f2bf(a.w);
    r[4] = f2bf(b.x); r[5] = f2bf(b.y); r[6] = f2bf(b.z); r[7] = f2bf(b.w);
    *(ushort8*)(dst + i) = r;
}

// ---------------------------------------------------------------------------
// Fused Q/K/V projection (blockIdx.z selects). out = (A @ W^T + b)*scale.
// z=0/1: bf16 scatter to [B,H,S,DK]. z=2: writes V^T [bh][dk][s] directly
// with the kappa+XOR key permutation folded in.
// BK=64: 16 K-iterations x 2 barriers (was 32x2) -> half the vmcnt(0)
// barrier drains, 32 MFMA per drain. Staging = attn's verified lp^lr8
// pattern (8x16B chunks/row, pre-swizzled global source, linear LDS dest);
// fragment reads XOR (ks*4+quad)^(row&7) -> 2-way bank alias (free).
// XCD-chunked block swizzle: each XCD gets 8 contiguous A-panels (2 MB) x
// all 8 W-panels (2 MB) -> working set == private L2.
// ---------------------------------------------------------------------------
__global__ __launch_bounds__(256) void gemm_proj(
    const ushort* __restrict__ qb, const ushort* __restrict__ kb,
    const ushort* __restrict__ vb, const ushort* __restrict__ Wb,
    const float* __restrict__ bq, const float* __restrict__ bk,
    const float* __restrict__ bv, ushort* __restrict__ Qd,
    ushort* __restrict__ Kd, ushort* __restrict__ Vt) {
    const int z = blockIdx.z;
    const ushort* A  = (z == 0) ? qb : (z == 1) ? kb : vb;
    const ushort* Wm = Wb + (size_t)z * (D_ * D_);
    const float* bias = (z == 0) ? bq : (z == 1) ? bk : bv;
    const float scale = (z == 0) ? QSCALE : 1.0f;

    __shared__ ushort As[128 * 64];
    __shared__ ushort Bs[128 * 64];
    const int t = threadIdx.x, w = t >> 6, lane = t & 63;
    const int ln15 = lane & 15, quad = lane >> 4;
    const int lp = lane & 7, lr8 = lane >> 3;
    const int wr = w >> 1, wc = w & 1;
    // XCD-chunked swizzle: lin%8 == dispatch XCD; give it y in [8k,8k+8)
    const int lin = blockIdx.y * 8 + blockIdx.x;  // 0..511
    const int jj_ = lin >> 3;                     // 0..63
    const int ny = (lin & 7) * 8 + (jj_ & 7);     // A-panel row block
    const int nx = jj_ >> 3;                      // W-panel col block
    const int n0 = nx * 128, m0 = ny * 128;
    const int sgs = (lp ^ lr8) * 8;  // pre-swizzled source chunk

    f32x4 acc[4][4] = {};
    for (int k0 = 0; k0 < D_; k0 += 64) {
#pragma unroll
        for (int ld = 0; ld < 4; ++ld) {
            const int row = ld * 32 + w * 8 + lr8;
            gl_lds16(A + (size_t)(m0 + row) * D_ + k0 + sgs, As + (ld * 4 + w) * 512);
            gl_lds16(Wm + (size_t)(n0 + row) * D_ + k0 + sgs, Bs + (ld * 4 + w) * 512);
        }
        __syncthreads();
#pragma unroll
        for (int ks = 0; ks < 2; ++ks) {
            short8 af[4], bf[4];
#pragma unroll
            for (int i = 0; i < 4; ++i) {
                const int ra = wr * 64 + i * 16 + ln15;
                af[i] = *(const short8*)(As + ra * 64 + (((ks * 4 + quad) ^ (ra & 7)) * 8));
                const int rb = wc * 64 + i * 16 + ln15;
                bf[i] = *(const short8*)(Bs + rb * 64 + (((ks * 4 + quad) ^ (rb & 7)) * 8));
            }
#pragma unroll
            for (int mt = 0; mt < 4; ++mt)
#pragma unroll
                for (int nt = 0; nt < 4; ++nt)
                    acc[mt][nt] = __builtin_amdgcn_mfma_f32_16x16x32_bf16(
                        af[mt], bf[nt], acc[mt][nt], 0, 0, 0);
        }
        __syncthreads();
    }
#pragma unroll
    for (int mt = 0; mt < 4; ++mt) {
#pragma unroll
        for (int r = 0; r < 4; ++r) {
            const int row = m0 + wr * 64 + mt * 16 + quad * 4 + r;
            const int bb = row >> 11, s = row & (S_ - 1);
            if (z == 2) {
                // inverse kappa: token-in-window m -> sg*8+j
                const int mm = s & 63, s0w = s & ~63;
                const int g2 = ((mm >> 2) & 1) | ((mm >> 3) & 2);
                const int sgi = ((mm >> 5) & 1) * 4 + g2;
                const int jj = (mm & 1) | ((mm >> 2) & 2) | ((mm << 1) & 4);
#pragma unroll
                for (int nt = 0; nt < 4; ++nt) {
                    const int col = n0 + wc * 64 + nt * 16 + ln15;
                    const float vv = acc[mt][nt][r] + bias[col];
                    const int h = col >> 6, dk = col & 63;
                    const int phys = ((sgi ^ (dk & 7)) << 3) | jj;
                    Vt[((((size_t)bb * H_ + h) * DK_ + dk) << 11) + s0w + phys] =
                        f2bf(vv);
                }
            } else {
#pragma unroll
                for (int nt = 0; nt < 4; ++nt) {
                    const int col = n0 + wc * 64 + nt * 16 + ln15;
                    const float vv = (acc[mt][nt][r] + bias[col]) * scale;
                    const int h = col >> 6, dk = col & 63;
                    ushort* outp = (z == 0) ? Qd : Kd;
                    outp[((((size_t)bb * H_ + h) * S_ + s) << 6) + dk] = f2bf(vv);
                }
            }
        }
    }
}

// ---------------------------------------------------------------------------
// Output projection: fp32 out = A @ W^T + b, flat [M,D]. Same BK=64
// structure, XCD swizzle, and staging swizzle as gemm_proj.
// ---------------------------------------------------------------------------
__global__ __launch_bounds__(256) void gemm_out(const ushort* __restrict__ A,
                                                const ushort* __restrict__ Wm,
                                                const float* __restrict__ bias,
                                                float* __restrict__ out) {
    __shared__ ushort As[128 * 64];
    __shared__ ushort Bs[128 * 64];
    const int t = threadIdx.x, w = t >> 6, lane = t & 63;
    const int ln15 = lane & 15, quad = lane >> 4;
    const int lp = lane & 7, lr8 = lane >> 3;
    const int wr = w >> 1, wc = w & 1;
    const int lin = blockIdx.y * 8 + blockIdx.x;  // 0..511
    const int jj_ = lin >> 3;
    const int ny = (lin & 7) * 8 + (jj_ & 7);
    const int nx = jj_ >> 3;
    const int n0 = nx * 128, m0 = ny * 128;
    const int sgs = (lp ^ lr8) * 8;

    f32x4 acc[4][4] = {};
    for (int k0 = 0; k0 < D_; k0 += 64) {
#pragma unroll
        for (int ld = 0; ld < 4; ++ld) {
            const int row = ld * 32 + w * 8 + lr8;
            gl_lds16(A + (size_t)(m0 + row) * D_ + k0 + sgs, As + (ld * 4 + w) * 512);
            gl_lds16(Wm + (size_t)(n0 + row) * D_ + k0 + sgs, Bs + (ld * 4 + w) * 512);
        }
        __syncthreads();
#pragma unroll
        for (int ks = 0; ks < 2; ++ks) {
            short8 af[4], bf[4];
#pragma unroll
            for (int i = 0; i < 4; ++i) {
                const int ra = wr * 64 + i * 16 + ln15;
                af[i] = *(const short8*)(As + ra * 64 + (((ks * 4 + quad) ^ (ra & 7)) * 8));
                const int rb = wc * 64 + i * 16 + ln15;
                bf[i] = *(const short8*)(Bs + rb * 64 + (((ks * 4 + quad) ^ (rb & 7)) * 8));
            }
#pragma unroll
            for (int mt = 0; mt < 4; ++mt)
#pragma unroll
                for (int nt = 0; nt < 4; ++nt)
                    acc[mt][nt] = __builtin_amdgcn_mfma_f32_16x16x32_bf16(
                        af[mt], bf[nt], acc[mt][nt], 0, 0, 0);
        }
        __syncthreads();
    }
#pragma unroll
    for (int mt = 0; mt < 4; ++mt) {
#pragma unroll
        for (int r = 0; r < 4; ++r) {
            const int row = m0 + wr * 64 + mt * 16 + quad * 4 + r;
#pragma unroll
            for (int nt = 0; nt < 4; ++nt) {
                const int col = n0 + wc * 64 + nt * 16 + ln15;
                out[(size_t)row * D_ + col] = acc[mt][nt][r] + bias[col];
            }
        }
    }
}

// ---------------------------------------------------------------------------
// Flash attention, no-LDS P path, fully mt-outer (round-5 verified).
// XCD-chunked swizzle: each XCD owns 8 bh (K+V = 4 MB, exactly L2).
// ---------------------------------------------------------------------------
__global__ __launch_bounds__(256, 4) void attn_mfma(
    const ushort* __restrict__ Qd, const ushort* __restrict__ Kd,
    const ushort* __restrict__ Vtg, const ushort* __restrict__ mpk,
    ushort* __restrict__ ctx) {
    __shared__ ushort Ks[2][64 * 64];  // [key][dk], swizzled groups
    __shared__ ushort Vt[2][64 * 64];  // [dk][key], swizzled groups

    const int t = threadIdx.x, w = t >> 6, lane = t & 63;
    const int ln15 = lane & 15, quad = lane >> 4;
    const int lp = lane & 7, lr8 = lane >> 3;
    // XCD-chunked: lin%8 == dispatch XCD -> bh in [8k, 8k+8), all 16 q-blocks
    const int lin = blockIdx.y * 16 + blockIdx.x;  // 0..1023
    const int jq = lin >> 3;                       // 0..127
    const int bh = (lin & 7) * 8 + (jq & 7);
    const int q0 = (jq >> 3) * 128;
    const int b = bh >> 4, h = bh & 15;

    const ushort* Qb = Qd + (size_t)bh * (S_ * DK_);
    const ushort* Kb = Kd + (size_t)bh * (S_ * DK_);
    const ushort* Vb = Vtg + (size_t)bh * (DK_ * S_);  // [dk][s] swizzled
    // packed mask: ushort at ((b*32 + kt)*2048 + qrow)*4 + quad
    const ushort* mb = mpk + (size_t)b * 32 * 2048 * 4;

    int mof[2];
#pragma unroll
    for (int mt = 0; mt < 2; ++mt)
        mof[mt] = ((q0 + w * 32 + mt * 16 + ln15) << 2) + quad;

    // Q fragments: loaded once, live in registers all kernel (B-operand)
    short8 aq[2][2];  // [ks][mt]
#pragma unroll
    for (int ks = 0; ks < 2; ++ks)
#pragma unroll
        for (int mt = 0; mt < 2; ++mt)
            aq[ks][mt] = *(const short8*)(
                Qb + (size_t)(q0 + w * 32 + mt * 16 + ln15) * DK_ + ks * 32 + quad * 8);

    // stage K/V tile kt into buffer p (async; drained by the NEXT barrier)
    auto stageKV = [&](int kt, int p) {
        const int k0 = kt * 64;
#pragma unroll
        for (int c = 0; c < 2; ++c) {
            const int cc = w * 2 + c;
            const int row = cc * 8 + lr8;  // K: key row; V: dk row
            gl_lds16(Kb + (size_t)(k0 + row) * DK_ + (lp ^ lr8) * 8, &Ks[p][cc * 512]);
            gl_lds16(Vb + (size_t)row * S_ + k0 + lp * 8, &Vt[p][cc * 512]);
        }
    };

    stageKV(0, 0);
    unsigned mv[2];
    mv[0] = mb[mof[0]];
    mv[1] = mb[mof[1]];

    f32x4 O[2][4] = {};
    f32x4 lsum[2] = {};
    short8 vone;
#pragma unroll
    for (int j = 0; j < 8; ++j) vone[j] = (short)0x3F80;  // bf16(1.0)

    int p = 0;
    for (int kt = 0; kt < S_ / 64; ++kt) {
        __syncthreads();  // drains stageKV(kt); buffer p^1 now free
        if (kt < S_ / 64 - 1) stageKV(kt + 1, p ^ 1);

#pragma unroll
        for (int mt = 0; mt < 2; ++mt) {
            // ---- S'^T = K (Q*QSCALE)^T for this mt
            f32x4 sc[4] = {};
            __builtin_amdgcn_s_setprio(1);
#pragma unroll
            for (int ks = 0; ks < 2; ++ks) {
#pragma unroll
                for (int nt = 0; nt < 4; ++nt) {
                    const int row = nt * 16 + ln15;
                    const short8 bk = *(const short8*)(
                        &Ks[p][row * 64 + ((ks * 4 + quad) ^ (row & 7)) * 8]);
                    sc[nt] = __builtin_amdgcn_mfma_f32_16x16x32_bf16(
                        bk, aq[ks][mt], sc[nt], 0, 0, 0);
                }
            }
            __builtin_amdgcn_s_setprio(0);

            // ---- P = maskbit ? exp2 : 0, pack bf16, permlane32 -> A-frags
            unsigned pk[4][2];
#pragma unroll
            for (int nt = 0; nt < 4; ++nt) {
                float pv[4];
#pragma unroll
                for (int r = 0; r < 4; ++r) {
                    const float e = __builtin_amdgcn_exp2f(sc[nt][r]);
                    // bit nt*4+r of mv -> 0 / 0xFFFFFFFF, AND with float bits
                    const unsigned msk =
                        (unsigned)((int)(mv[mt] << (31 - (nt * 4 + r))) >> 31);
                    pv[r] = __uint_as_float(__float_as_uint(e) & msk);
                }
                pk[nt][0] = cvt_pk_bf16(pv[0], pv[1]);
                pk[nt][1] = cvt_pk_bf16(pv[2], pv[3]);
            }
            pl32_swap(pk[0][0], pk[1][0]);
            pl32_swap(pk[0][1], pk[1][1]);
            pl32_swap(pk[2][0], pk[3][0]);
            pl32_swap(pk[2][1], pk[3][1]);
            const short8 ap0 = mk8(pk[0][0], pk[1][0], pk[0][1], pk[1][1]);
            const short8 ap1 = mk8(pk[2][0], pk[3][0], pk[2][1], pk[3][1]);

            // ---- O[mt] += P V^T ; lsum[mt] += P @ ones
#pragma unroll
            for (int ks = 0; ks < 2; ++ks) {
                const short8 apx = ks ? ap1 : ap0;
                short8 bv4[4];
#pragma unroll
                for (int nt = 0; nt < 4; ++nt) {
                    const int dim = nt * 16 + ln15;
                    bv4[nt] = *(const short8*)(
                        &Vt[p][dim * 64 + ((ks * 4 + quad) ^ (dim & 7)) * 8]);
                }
                __builtin_amdgcn_s_setprio(1);
#pragma unroll
                for (int nt = 0; nt < 4; ++nt)
                    O[mt][nt] = __builtin_amdgcn_mfma_f32_16x16x32_bf16(
                        apx, bv4[nt], O[mt][nt], 0, 0, 0);
                lsum[mt] = __builtin_amdgcn_mfma_f32_16x16x32_bf16(
                    apx, vone, lsum[mt], 0, 0, 0);
                __builtin_amdgcn_s_setprio(0);
            }
        }

        // prefetch mask for kt+1 (both mv dead here)
        if (kt < S_ / 64 - 1) {
            mv[0] = mb[(kt + 1) * 8192 + mof[0]];
            mv[1] = mb[(kt + 1) * 8192 + mof[1]];
        }
        p ^= 1;
    }

    // finalize: ctx[b][s][h*64+dim] = O / lsum (bf16, feeds out-proj)
#pragma unroll
    for (int mt = 0; mt < 2; ++mt) {
#pragma unroll
        for (int r = 0; r < 4; ++r) {
            const int qg = q0 + w * 32 + mt * 16 + quad * 4 + r;
            const float inv = __builtin_amdgcn_rcpf(lsum[mt][r]);
#pragma unroll
            for (int nt = 0; nt < 4; ++nt) {
                const int dim = nt * 16 + ln15;
                ctx[((size_t)b * S_ + qg) * D_ + h * DK_ + dim] = f2bf(O[mt][nt][r] * inv);
            }
        }
    }
}

// ---------------------------------------------------------------------------
extern "C" void kernel_launch(void* const* d_in, const int* in_sizes, int n_in,
                              void* d_out, int out_size, void* d_ws, size_t ws_size,
                              hipStream_t stream) {
    (void)in_sizes; (void)n_in; (void)out_size; (void)ws_size;
    const float* query = (const float*)d_in[0];
    const float* key_  = (const float*)d_in[1];
    const float* value = (const float*)d_in[2];
    const int*   mask  = (const int*)d_in[3];
    const float* Wq = (const float*)d_in[4];
    const float* bq = (const float*)d_in[5];
    const float* Wk = (const float*)d_in[6];
    const float* bk = (const float*)d_in[7];
    const float* Wv = (const float*)d_in[8];
    const float* bv = (const float*)d_in[9];
    const float* Wo = (const float*)d_in[10];
    const float* bo = (const float*)d_in[11];
    float* out = (float*)d_out;

    const size_t nX = (size_t)B_ * S_ * D_;  // 8,388,608
    const size_t nW = (size_t)D_ * D_;       // 1,048,576
    ushort* qkv = (ushort*)d_ws;       // 3*nX bf16 (q,k,v casts)
    ushort* Wb  = qkv + 3 * nX;        // 4*nW bf16
    ushort* Qd  = Wb + 4 * nW;
    ushort* Kd  = Qd + nX;
    ushort* Vt  = Kd + nX;             // V^T [bh][dk][s], kappa+XOR permuted
    unsigned long long* mpk = (unsigned long long*)(Vt + nX);  // 2 MB
    ushort* ctx = qkv;                 // q-cast region, dead after gemm_proj

    // 14336 cast blocks + 65536 mask blocks (B*S*S/256)
    cast_mask<<<79872, 256, 0, stream>>>(query, key_, value, Wq, Wk, Wv, Wo,
                                         mask, qkv, Wb, mpk);

    dim3 gp(D_ / 128, (B_ * S_) / 128, 3);  // (8, 64, 3)
    gemm_proj<<<gp, 256, 0, stream>>>(qkv, qkv + nX, qkv + 2 * nX, Wb,
                                      bq, bk, bv, Qd, Kd, Vt);

    dim3 ga(S_ / 128, B_ * H_);  // (16, 64)
    attn_mfma<<<ga, 256, 0, stream>>>(Qd, Kd, Vt, (const ushort*)mpk, ctx);

    dim3 go(D_ / 128, (B_ * S_) / 128);  // (8, 64)
    gemm_out<<<go, 256, 0, stream>>>(ctx, Wb + 3 * nW, bo, out);
}

// Round 8
// 410.389 us; speedup vs baseline: 1.4519x; 1.0138x over previous
//
#include <hip/hip_runtime.h>

#define B_  4
#define S_  2048
#define D_  1024
#define H_  16
#define DK_ 64

typedef unsigned short ushort;
typedef __attribute__((ext_vector_type(8))) short short8;
typedef __attribute__((ext_vector_type(8))) unsigned short ushort8;
typedef __attribute__((ext_vector_type(4))) float f32x4;

// scores use exp2: fold 0.125 * log2(e) into Q at projection time
#define QSCALE 0.18033688011112042f

__device__ __forceinline__ ushort f2bf(float f) {  // RNE
    unsigned int u = __float_as_uint(f);
    u += 0x7fffu + ((u >> 16) & 1u);
    return (ushort)(u >> 16);
}

__device__ __forceinline__ unsigned cvt_pk_bf16(float lo, float hi) {
    unsigned r;
    asm("v_cvt_pk_bf16_f32 %0, %1, %2" : "=v"(r) : "v"(lo), "v"(hi));
    return r;
}
// swaps a[32:63] <-> b[0:31]
__device__ __forceinline__ void pl32_swap(unsigned& a, unsigned& b) {
    asm("v_permlane32_swap_b32 %0, %1" : "+v"(a), "+v"(b));
}
__device__ __forceinline__ short8 mk8(unsigned a, unsigned b, unsigned c,
                                      unsigned d) {
    union { unsigned u[4]; short8 s; } x;
    x.u[0] = a; x.u[1] = b; x.u[2] = c; x.u[3] = d;
    return x.s;
}

__device__ __forceinline__ void gl_lds16(const ushort* g, ushort* ldsbase) {
    __builtin_amdgcn_global_load_lds(
        (const __attribute__((address_space(1))) void*)g,
        (__attribute__((address_space(3))) void*)ldsbase, 16, 0, 0);
}

// ---------------------------------------------------------------------------
// Merged: cast q,k,v + Wq,Wk,Wv,Wo to bf16 (blocks 0..14335) AND mask pack
// (blocks 14336..79871 — 65536 mask blocks, B*S*S/256). Mask pack: per
// 64-key window, lane L reads key kappa(L) so __ballot directly yields the
// quad-chunked word: bit (quad*16 + nt*4 + r) = mask at key
// (nt*16 + quad*4 + r). Layout mpk[b][kt][q] (ull) -> attn reads ONE
// ushort: [b][kt][q][quad].
// ---------------------------------------------------------------------------
__global__ __launch_bounds__(256) void cast_mask(
    const float* __restrict__ q, const float* __restrict__ k,
    const float* __restrict__ v, const float* __restrict__ Wq,
    const float* __restrict__ Wk, const float* __restrict__ Wv,
    const float* __restrict__ Wo, const int* __restrict__ m,
    ushort* __restrict__ qkv_dst, ushort* __restrict__ w_dst,
    unsigned long long* __restrict__ mpk) {
    int bid = blockIdx.x;
    if (bid >= 14336) {  // ---- mask pack path (65536 blocks)
        bid -= 14336;
        const size_t idx = (size_t)bid * 256 + threadIdx.x;
        const int lane = threadIdx.x & 63;
        const size_t wbase = idx & ~(size_t)63;
        const int kap = (((lane >> 2) & 3) << 4) | ((lane >> 4) << 2) | (lane & 3);
        const unsigned long long W = __ballot(m[wbase + kap] != 0);
        if (lane == 0) {
            const size_t widx = wbase >> 6;
            const int kt = (int)(widx & 31);
            const int qq = (int)((widx >> 5) & 2047);
            const int bb = (int)(widx >> 16);
            mpk[((size_t)bb * 32 + kt) * 2048 + qq] = W;
        }
        return;
    }
    const float* src;
    ushort* dst;
    int lb;
    if (bid < 12288) {
        const int s = bid >> 12;
        lb = bid & 4095;
        src = (s == 0) ? q : (s == 1) ? k : v;
        dst = qkv_dst + (size_t)s * (B_ * S_ * D_);
    } else {
        const int wi = (bid - 12288) >> 9;
        lb = (bid - 12288) & 511;
        src = (wi == 0) ? Wq : (wi == 1) ? Wk : (wi == 2) ? Wv : Wo;
        dst = w_dst + (size_t)wi * (D_ * D_);
    }
    const int i = lb * 2048 + threadIdx.x * 8;
    const float4 a = *(const float4*)(src + i);
    const float4 b = *(const float4*)(src + i + 4);
    ushort8 r;
    r[0] = f2bf(a.x); r[1] = f2bf(a.y); r[2] = f2bf(a.z); r[3] = f2bf(a.w);
    r[4] = f2bf(b.x); r[5] = f2bf(b.y); r[6] = f2bf(b.z); r[7] = f2bf(b.w);
    *(ushort8*)(dst + i) = r;
}

// ---------------------------------------------------------------------------
// Fused Q/K/V projection (blockIdx.z selects). out = (A @ W^T + b)*scale.
// z=0/1: bf16 scatter to [B,H,S,DK]. z=2: writes V^T [bh][dk][s] directly
// with the kappa+XOR key permutation folded in.
// 2-phase double-buffered (attn-style): stage(k0+32) issued right after the
// barrier, compute(k0) overlaps the staging latency; loads drain at the NEXT
// barrier, one compute-phase later. LDS 32 KB (same as single-buffered BK=64
// -> occupancy unchanged). Staging/read = round-6 verified 4-chunk XOR.
// XCD-chunked block swizzle: each XCD gets 8 contiguous A-panels (2 MB) x
// all 8 W-panels (2 MB) -> working set == private L2.
// ---------------------------------------------------------------------------
__global__ __launch_bounds__(256) void gemm_proj(
    const ushort* __restrict__ qb, const ushort* __restrict__ kb,
    const ushort* __restrict__ vb, const ushort* __restrict__ Wb,
    const float* __restrict__ bq, const float* __restrict__ bk,
    const float* __restrict__ bv, ushort* __restrict__ Qd,
    ushort* __restrict__ Kd, ushort* __restrict__ Vt) {
    const int z = blockIdx.z;
    const ushort* A  = (z == 0) ? qb : (z == 1) ? kb : vb;
    const ushort* Wm = Wb + (size_t)z * (D_ * D_);
    const float* bias = (z == 0) ? bq : (z == 1) ? bk : bv;
    const float scale = (z == 0) ? QSCALE : 1.0f;

    __shared__ ushort As[2][128 * 32];
    __shared__ ushort Bs[2][128 * 32];
    const int t = threadIdx.x, w = t >> 6, lane = t & 63;
    const int ln15 = lane & 15, quad = lane >> 4;
    const int wr = w >> 1, wc = w & 1;
    // XCD-chunked swizzle: lin%8 == dispatch XCD; give it y in [8k,8k+8)
    const int lin = blockIdx.y * 8 + blockIdx.x;  // 0..511
    const int jj_ = lin >> 3;                     // 0..63
    const int ny = (lin & 7) * 8 + (jj_ & 7);     // A-panel row block
    const int nx = jj_ >> 3;                      // W-panel col block
    const int n0 = nx * 128, m0 = ny * 128;
    const int srow = lane >> 2;
    // pre-swizzled source chunk: physical chunk (lane&3) holds logical
    // chunk (lane&3)^(srow&3)
    const int sgs = ((lane & 3) ^ (srow & 3)) * 8;
    const int cx = ln15 & 3;  // read-side XOR key (row&3)

    auto stage = [&](int k0, int pp) {
#pragma unroll
        for (int c = 0; c < 2; ++c) {
            const int cc = w * 2 + c;
            const int row = cc * 16 + srow;
            gl_lds16(A + (size_t)(m0 + row) * D_ + k0 + sgs, &As[pp][cc * 512]);
            gl_lds16(Wm + (size_t)(n0 + row) * D_ + k0 + sgs, &Bs[pp][cc * 512]);
        }
    };

    f32x4 acc[4][4] = {};
    stage(0, 0);
    int p = 0;
    for (int k0 = 0; k0 < D_; k0 += 32) {
        __syncthreads();  // drains stage(k0); buffer p^1 free for restage
        if (k0 + 32 < D_) stage(k0 + 32, p ^ 1);
        short8 af[4], bf[4];
#pragma unroll
        for (int i = 0; i < 4; ++i) {
            af[i] = *(const short8*)(&As[p][(wr * 64 + i * 16 + ln15) * 32 + (quad ^ cx) * 8]);
            bf[i] = *(const short8*)(&Bs[p][(wc * 64 + i * 16 + ln15) * 32 + (quad ^ cx) * 8]);
        }
#pragma unroll
        for (int mt = 0; mt < 4; ++mt)
#pragma unroll
            for (int nt = 0; nt < 4; ++nt)
                acc[mt][nt] = __builtin_amdgcn_mfma_f32_16x16x32_bf16(
                    af[mt], bf[nt], acc[mt][nt], 0, 0, 0);
        p ^= 1;
    }
#pragma unroll
    for (int mt = 0; mt < 4; ++mt) {
#pragma unroll
        for (int r = 0; r < 4; ++r) {
            const int row = m0 + wr * 64 + mt * 16 + quad * 4 + r;
            const int bb = row >> 11, s = row & (S_ - 1);
            if (z == 2) {
                // inverse kappa: token-in-window m -> sg*8+j
                const int mm = s & 63, s0w = s & ~63;
                const int g2 = ((mm >> 2) & 1) | ((mm >> 3) & 2);
                const int sgi = ((mm >> 5) & 1) * 4 + g2;
                const int jj = (mm & 1) | ((mm >> 2) & 2) | ((mm << 1) & 4);
#pragma unroll
                for (int nt = 0; nt < 4; ++nt) {
                    const int col = n0 + wc * 64 + nt * 16 + ln15;
                    const float vv = acc[mt][nt][r] + bias[col];
                    const int h = col >> 6, dk = col & 63;
                    const int phys = ((sgi ^ (dk & 7)) << 3) | jj;
                    Vt[((((size_t)bb * H_ + h) * DK_ + dk) << 11) + s0w + phys] =
                        f2bf(vv);
                }
            } else {
#pragma unroll
                for (int nt = 0; nt < 4; ++nt) {
                    const int col = n0 + wc * 64 + nt * 16 + ln15;
                    const float vv = (acc[mt][nt][r] + bias[col]) * scale;
                    const int h = col >> 6, dk = col & 63;
                    ushort* outp = (z == 0) ? Qd : Kd;
                    outp[((((size_t)bb * H_ + h) * S_ + s) << 6) + dk] = f2bf(vv);
                }
            }
        }
    }
}

// ---------------------------------------------------------------------------
// Output projection: fp32 out = A @ W^T + b, flat [M,D]. Same 2-phase dbuf
// structure, XCD swizzle, and staging swizzle as gemm_proj.
// ---------------------------------------------------------------------------
__global__ __launch_bounds__(256) void gemm_out(const ushort* __restrict__ A,
                                                const ushort* __restrict__ Wm,
                                                const float* __restrict__ bias,
                                                float* __restrict__ out) {
    __shared__ ushort As[2][128 * 32];
    __shared__ ushort Bs[2][128 * 32];
    const int t = threadIdx.x, w = t >> 6, lane = t & 63;
    const int ln15 = lane & 15, quad = lane >> 4;
    const int wr = w >> 1, wc = w & 1;
    const int lin = blockIdx.y * 8 + blockIdx.x;  // 0..511
    const int jj_ = lin >> 3;
    const int ny = (lin & 7) * 8 + (jj_ & 7);
    const int nx = jj_ >> 3;
    const int n0 = nx * 128, m0 = ny * 128;
    const int srow = lane >> 2;
    const int sgs = ((lane & 3) ^ (srow & 3)) * 8;
    const int cx = ln15 & 3;

    auto stage = [&](int k0, int pp) {
#pragma unroll
        for (int c = 0; c < 2; ++c) {
            const int cc = w * 2 + c;
            const int row = cc * 16 + srow;
            gl_lds16(A + (size_t)(m0 + row) * D_ + k0 + sgs, &As[pp][cc * 512]);
            gl_lds16(Wm + (size_t)(n0 + row) * D_ + k0 + sgs, &Bs[pp][cc * 512]);
        }
    };

    f32x4 acc[4][4] = {};
    stage(0, 0);
    int p = 0;
    for (int k0 = 0; k0 < D_; k0 += 32) {
        __syncthreads();
        if (k0 + 32 < D_) stage(k0 + 32, p ^ 1);
        short8 af[4], bf[4];
#pragma unroll
        for (int i = 0; i < 4; ++i) {
            af[i] = *(const short8*)(&As[p][(wr * 64 + i * 16 + ln15) * 32 + (quad ^ cx) * 8]);
            bf[i] = *(const short8*)(&Bs[p][(wc * 64 + i * 16 + ln15) * 32 + (quad ^ cx) * 8]);
        }
#pragma unroll
        for (int mt = 0; mt < 4; ++mt)
#pragma unroll
            for (int nt = 0; nt < 4; ++nt)
                acc[mt][nt] = __builtin_amdgcn_mfma_f32_16x16x32_bf16(
                    af[mt], bf[nt], acc[mt][nt], 0, 0, 0);
        p ^= 1;
    }
#pragma unroll
    for (int mt = 0; mt < 4; ++mt) {
#pragma unroll
        for (int r = 0; r < 4; ++r) {
            const int row = m0 + wr * 64 + mt * 16 + quad * 4 + r;
#pragma unroll
            for (int nt = 0; nt < 4; ++nt) {
                const int col = n0 + wc * 64 + nt * 16 + ln15;
                out[(size_t)row * D_ + col] = acc[mt][nt][r] + bias[col];
            }
        }
    }
}

// ---------------------------------------------------------------------------
// Flash attention, no-LDS P path, fully mt-outer (round-5 verified).
// XCD-chunked swizzle: each XCD owns 8 bh (K+V = 4 MB, exactly L2).
// ---------------------------------------------------------------------------
__global__ __launch_bounds__(256, 4) void attn_mfma(
    const ushort* __restrict__ Qd, const ushort* __restrict__ Kd,
    const ushort* __restrict__ Vtg, const ushort* __restrict__ mpk,
    ushort* __restrict__ ctx) {
    __shared__ ushort Ks[2][64 * 64];  // [key][dk], swizzled groups
    __shared__ ushort Vt[2][64 * 64];  // [dk][key], swizzled groups

    const int t = threadIdx.x, w = t >> 6, lane = t & 63;
    const int ln15 = lane & 15, quad = lane >> 4;
    const int lp = lane & 7, lr8 = lane >> 3;
    // XCD-chunked: lin%8 == dispatch XCD -> bh in [8k, 8k+8), all 16 q-blocks
    const int lin = blockIdx.y * 16 + blockIdx.x;  // 0..1023
    const int jq = lin >> 3;                       // 0..127
    const int bh = (lin & 7) * 8 + (jq & 7);
    const int q0 = (jq >> 3) * 128;
    const int b = bh >> 4, h = bh & 15;

    const ushort* Qb = Qd + (size_t)bh * (S_ * DK_);
    const ushort* Kb = Kd + (size_t)bh * (S_ * DK_);
    const ushort* Vb = Vtg + (size_t)bh * (DK_ * S_);  // [dk][s] swizzled
    // packed mask: ushort at ((b*32 + kt)*2048 + qrow)*4 + quad
    const ushort* mb = mpk + (size_t)b * 32 * 2048 * 4;

    int mof[2];
#pragma unroll
    for (int mt = 0; mt < 2; ++mt)
        mof[mt] = ((q0 + w * 32 + mt * 16 + ln15) << 2) + quad;

    // Q fragments: loaded once, live in registers all kernel (B-operand)
    short8 aq[2][2];  // [ks][mt]
#pragma unroll
    for (int ks = 0; ks < 2; ++ks)
#pragma unroll
        for (int mt = 0; mt < 2; ++mt)
            aq[ks][mt] = *(const short8*)(
                Qb + (size_t)(q0 + w * 32 + mt * 16 + ln15) * DK_ + ks * 32 + quad * 8);

    // stage K/V tile kt into buffer p (async; drained by the NEXT barrier)
    auto stageKV = [&](int kt, int p) {
        const int k0 = kt * 64;
#pragma unroll
        for (int c = 0; c < 2; ++c) {
            const int cc = w * 2 + c;
            const int row = cc * 8 + lr8;  // K: key row; V: dk row
            gl_lds16(Kb + (size_t)(k0 + row) * DK_ + (lp ^ lr8) * 8, &Ks[p][cc * 512]);
            gl_lds16(Vb + (size_t)row * S_ + k0 + lp * 8, &Vt[p][cc * 512]);
        }
    };

    stageKV(0, 0);
    unsigned mv[2];
    mv[0] = mb[mof[0]];
    mv[1] = mb[mof[1]];

    f32x4 O[2][4] = {};
    f32x4 lsum[2] = {};
    short8 vone;
#pragma unroll
    for (int j = 0; j < 8; ++j) vone[j] = (short)0x3F80;  // bf16(1.0)

    int p = 0;
    for (int kt = 0; kt < S_ / 64; ++kt) {
        __syncthreads();  // drains stageKV(kt); buffer p^1 now free
        if (kt < S_ / 64 - 1) stageKV(kt + 1, p ^ 1);

#pragma unroll
        for (int mt = 0; mt < 2; ++mt) {
            // ---- S'^T = K (Q*QSCALE)^T for this mt
            f32x4 sc[4] = {};
            __builtin_amdgcn_s_setprio(1);
#pragma unroll
            for (int ks = 0; ks < 2; ++ks) {
#pragma unroll
                for (int nt = 0; nt < 4; ++nt) {
                    const int row = nt * 16 + ln15;
                    const short8 bk = *(const short8*)(
                        &Ks[p][row * 64 + ((ks * 4 + quad) ^ (row & 7)) * 8]);
                    sc[nt] = __builtin_amdgcn_mfma_f32_16x16x32_bf16(
                        bk, aq[ks][mt], sc[nt], 0, 0, 0);
                }
            }
            __builtin_amdgcn_s_setprio(0);

            // ---- P = maskbit ? exp2 : 0, pack bf16, permlane32 -> A-frags
            unsigned pk[4][2];
#pragma unroll
            for (int nt = 0; nt < 4; ++nt) {
                float pv[4];
#pragma unroll
                for (int r = 0; r < 4; ++r) {
                    const float e = __builtin_amdgcn_exp2f(sc[nt][r]);
                    // bit nt*4+r of mv -> 0 / 0xFFFFFFFF, AND with float bits
                    const unsigned msk =
                        (unsigned)((int)(mv[mt] << (31 - (nt * 4 + r))) >> 31);
                    pv[r] = __uint_as_float(__float_as_uint(e) & msk);
                }
                pk[nt][0] = cvt_pk_bf16(pv[0], pv[1]);
                pk[nt][1] = cvt_pk_bf16(pv[2], pv[3]);
            }
            pl32_swap(pk[0][0], pk[1][0]);
            pl32_swap(pk[0][1], pk[1][1]);
            pl32_swap(pk[2][0], pk[3][0]);
            pl32_swap(pk[2][1], pk[3][1]);
            const short8 ap0 = mk8(pk[0][0], pk[1][0], pk[0][1], pk[1][1]);
            const short8 ap1 = mk8(pk[2][0], pk[3][0], pk[2][1], pk[3][1]);

            // ---- O[mt] += P V^T ; lsum[mt] += P @ ones
#pragma unroll
            for (int ks = 0; ks < 2; ++ks) {
                const short8 apx = ks ? ap1 : ap0;
                short8 bv4[4];
#pragma unroll
                for (int nt = 0; nt < 4; ++nt) {
                    const int dim = nt * 16 + ln15;
                    bv4[nt] = *(const short8*)(
                        &Vt[p][dim * 64 + ((ks * 4 + quad) ^ (dim & 7)) * 8]);
                }
                __builtin_amdgcn_s_setprio(1);
#pragma unroll
                for (int nt = 0; nt < 4; ++nt)
                    O[mt][nt] = __builtin_amdgcn_mfma_f32_16x16x32_bf16(
                        apx, bv4[nt], O[mt][nt], 0, 0, 0);
                lsum[mt] = __builtin_amdgcn_mfma_f32_16x16x32_bf16(
                    apx, vone, lsum[mt], 0, 0, 0);
                __builtin_amdgcn_s_setprio(0);
            }
        }

        // prefetch mask for kt+1 (both mv dead here)
        if (kt < S_ / 64 - 1) {
            mv[0] = mb[(kt + 1) * 8192 + mof[0]];
            mv[1] = mb[(kt + 1) * 8192 + mof[1]];
        }
        p ^= 1;
    }

    // finalize: ctx[b][s][h*64+dim] = O / lsum (bf16, feeds out-proj)
#pragma unroll
    for (int mt = 0; mt < 2; ++mt) {
#pragma unroll
        for (int r = 0; r < 4; ++r) {
            const int qg = q0 + w * 32 + mt * 16 + quad * 4 + r;
            const float inv = __builtin_amdgcn_rcpf(lsum[mt][r]);
#pragma unroll
            for (int nt = 0; nt < 4; ++nt) {
                const int dim = nt * 16 + ln15;
                ctx[((size_t)b * S_ + qg) * D_ + h * DK_ + dim] = f2bf(O[mt][nt][r] * inv);
            }
        }
    }
}

// ---------------------------------------------------------------------------
extern "C" void kernel_launch(void* const* d_in, const int* in_sizes, int n_in,
                              void* d_out, int out_size, void* d_ws, size_t ws_size,
                              hipStream_t stream) {
    (void)in_sizes; (void)n_in; (void)out_size; (void)ws_size;
    const float* query = (const float*)d_in[0];
    const float* key_  = (const float*)d_in[1];
    const float* value = (const float*)d_in[2];
    const int*   mask  = (const int*)d_in[3];
    const float* Wq = (const float*)d_in[4];
    const float* bq = (const float*)d_in[5];
    const float* Wk = (const float*)d_in[6];
    const float* bk = (const float*)d_in[7];
    const float* Wv = (const float*)d_in[8];
    const float* bv = (const float*)d_in[9];
    const float* Wo = (const float*)d_in[10];
    const float* bo = (const float*)d_in[11];
    float* out = (float*)d_out;

    const size_t nX = (size_t)B_ * S_ * D_;  // 8,388,608
    const size_t nW = (size_t)D_ * D_;       // 1,048,576
    ushort* qkv = (ushort*)d_ws;       // 3*nX bf16 (q,k,v casts)
    ushort* Wb  = qkv + 3 * nX;        // 4*nW bf16
    ushort* Qd  = Wb + 4 * nW;
    ushort* Kd  = Qd + nX;
    ushort* Vt  = Kd + nX;             // V^T [bh][dk][s], kappa+XOR permuted
    unsigned long long* mpk = (unsigned long long*)(Vt + nX);  // 2 MB
    ushort* ctx = qkv;                 // q-cast region, dead after gemm_proj

    // 14336 cast blocks + 65536 mask blocks (B*S*S/256)
    cast_mask<<<79872, 256, 0, stream>>>(query, key_, value, Wq, Wk, Wv, Wo,
                                         mask, qkv, Wb, mpk);

    dim3 gp(D_ / 128, (B_ * S_) / 128, 3);  // (8, 64, 3)
    gemm_proj<<<gp, 256, 0, stream>>>(qkv, qkv + nX, qkv + 2 * nX, Wb,
                                      bq, bk, bv, Qd, Kd, Vt);

    dim3 ga(S_ / 128, B_ * H_);  // (16, 64)
    attn_mfma<<<ga, 256, 0, stream>>>(Qd, Kd, Vt, (const ushort*)mpk, ctx);

    dim3 go(D_ / 128, (B_ * S_) / 128);  // (8, 64)
    gemm_out<<<go, 256, 0, stream>>>(ctx, Wb + 3 * nW, bo, out);
}